// Round 1
// baseline (1426.598 us; speedup 1.0000x reference)
//
#include <hip/hip_runtime.h>
#include <hip/hip_bf16.h>

// Problem constants (MultiAttention_61340722921598)
#define BATCH 2
#define SEQ   2048
#define DMODEL 1024
#define NHEADS 16
#define HDIM   64
#define WINDOW 128
#define ROWS  (BATCH * SEQ)          // 4096

// ---------------------------------------------------------------------------
// fp32 tiled GEMM: C[m][n] = sum_k X[m][k] * W[n][k]  (+ optional bias[n])
// BM=BN=64, BK=16, 256 threads, 4x4 microtile per thread.
// Baseline: correctness-focused; round-2 will replace with bf16 MFMA.
// ---------------------------------------------------------------------------
__device__ __forceinline__ void gemm_body(const float* __restrict__ X,
                                          const float* __restrict__ W,
                                          float* __restrict__ C,
                                          const float* __restrict__ bias,
                                          int M, int N, int K)
{
    __shared__ float Xs[16][65];   // [k][m], +1 pad to break bank conflicts
    __shared__ float Ws[16][65];   // [k][n]

    const int tid = threadIdx.x;
    const int m0 = blockIdx.y * 64;
    const int n0 = blockIdx.x * 64;
    const int tx = tid & 15;        // n-direction (4 cols each)
    const int ty = tid >> 4;        // m-direction (4 rows each)

    const int lrow = tid >> 2;          // 0..63
    const int lcol = (tid & 3) * 4;     // 0,4,8,12

    const float* Xp = X + (size_t)(m0 + lrow) * K + lcol;
    const float* Wp = W + (size_t)(n0 + lrow) * K + lcol;

    float acc[4][4] = {};

    for (int k0 = 0; k0 < K; k0 += 16) {
        float4 xv = *(const float4*)(Xp + k0);
        float4 wv = *(const float4*)(Wp + k0);
        __syncthreads();   // previous iter's reads done before overwrite
        Xs[lcol + 0][lrow] = xv.x; Xs[lcol + 1][lrow] = xv.y;
        Xs[lcol + 2][lrow] = xv.z; Xs[lcol + 3][lrow] = xv.w;
        Ws[lcol + 0][lrow] = wv.x; Ws[lcol + 1][lrow] = wv.y;
        Ws[lcol + 2][lrow] = wv.z; Ws[lcol + 3][lrow] = wv.w;
        __syncthreads();
#pragma unroll
        for (int kk = 0; kk < 16; ++kk) {
            float a0 = Xs[kk][ty * 4 + 0];
            float a1 = Xs[kk][ty * 4 + 1];
            float a2 = Xs[kk][ty * 4 + 2];
            float a3 = Xs[kk][ty * 4 + 3];
            float b0 = Ws[kk][tx * 4 + 0];
            float b1 = Ws[kk][tx * 4 + 1];
            float b2 = Ws[kk][tx * 4 + 2];
            float b3 = Ws[kk][tx * 4 + 3];
            acc[0][0] += a0 * b0; acc[0][1] += a0 * b1; acc[0][2] += a0 * b2; acc[0][3] += a0 * b3;
            acc[1][0] += a1 * b0; acc[1][1] += a1 * b1; acc[1][2] += a1 * b2; acc[1][3] += a1 * b3;
            acc[2][0] += a2 * b0; acc[2][1] += a2 * b1; acc[2][2] += a2 * b2; acc[2][3] += a2 * b3;
            acc[3][0] += a3 * b0; acc[3][1] += a3 * b1; acc[3][2] += a3 * b2; acc[3][3] += a3 * b3;
        }
    }

#pragma unroll
    for (int i = 0; i < 4; ++i) {
        int m = m0 + ty * 4 + i;
        float4 r;
        r.x = acc[i][0]; r.y = acc[i][1]; r.z = acc[i][2]; r.w = acc[i][3];
        if (bias) {
            const float* bp = bias + n0 + tx * 4;
            r.x += bp[0]; r.y += bp[1]; r.z += bp[2]; r.w += bp[3];
        }
        *(float4*)(C + (size_t)m * N + n0 + tx * 4) = r;
    }
}

__global__ __launch_bounds__(256) void gemm_qkv(
    const float* __restrict__ X,
    const float* __restrict__ W0, const float* __restrict__ W1,
    const float* __restrict__ W2,
    float* __restrict__ C0, float* __restrict__ C1, float* __restrict__ C2)
{
    const float* W = (blockIdx.z == 0) ? W0 : ((blockIdx.z == 1) ? W1 : W2);
    float*       C = (blockIdx.z == 0) ? C0 : ((blockIdx.z == 1) ? C1 : C2);
    gemm_body(X, W, C, nullptr, ROWS, DMODEL, DMODEL);
}

__global__ __launch_bounds__(256) void gemm_out(
    const float* __restrict__ X, const float* __restrict__ W,
    const float* __restrict__ bias, float* __restrict__ C)
{
    gemm_body(X, W, C, bias, ROWS, DMODEL, DMODEL);
}

// ---------------------------------------------------------------------------
// RoPE applied in-place to Q and K. One thread per (row, head, pair d<32).
// q'[d]    = q[d]*cos - q[d+32]*sin
// q'[d+32] = q[d+32]*cos + q[d]*sin,  angle = t * 10000^(-d/32)
// ---------------------------------------------------------------------------
__global__ void rope_kernel(float* __restrict__ Q, float* __restrict__ K)
{
    int idx = blockIdx.x * blockDim.x + threadIdx.x;
    if (idx >= ROWS * NHEADS * 32) return;
    int d   = idx & 31;
    int h   = (idx >> 5) & 15;
    int row = idx >> 9;          // 0..4095
    int t   = row & (SEQ - 1);

    // inv_freq = 10000^(-2i/64); ln(10000)/32 = 0.28782313662425572
    float inv = expf(-(float)d * 0.28782313662425572f);
    float ang = (float)t * inv;
    float s, c;
    sincosf(ang, &s, &c);        // accurate libm version (large-arg reduction)

    size_t i0 = (size_t)row * DMODEL + h * HDIM + d;
    size_t i1 = i0 + 32;

    float q0 = Q[i0], q1 = Q[i1];
    Q[i0] = q0 * c - q1 * s;
    Q[i1] = q1 * c + q0 * s;

    float k0 = K[i0], k1 = K[i1];
    K[i0] = k0 * c - k1 * s;
    K[i1] = k1 * c + k0 * s;
}

// ---------------------------------------------------------------------------
// Sliding-window attention, one wave (64 lanes) per (b, h, t).
// Lane l owns dim l of the head. Scores via butterfly reduce; softmax in
// registers (2 score slots/lane covers the <=128-key window); PV coalesced.
// ---------------------------------------------------------------------------
__global__ __launch_bounds__(64) void attn_kernel(
    const float* __restrict__ Q, const float* __restrict__ K,
    const float* __restrict__ V, float* __restrict__ O)
{
    const int lane = threadIdx.x;
    const int t = blockIdx.x;
    const int h = blockIdx.y;
    const int b = blockIdx.z;
    const int row = b * SEQ + t;
    const size_t base = (size_t)row * DMODEL + h * HDIM;

    const float sm = 0.125f;     // 1/sqrt(64)
    float q = Q[base + lane] * sm;

    const int jstart = (t >= WINDOW - 1) ? (t - (WINDOW - 1)) : 0;
    const int nk = t - jstart + 1;   // 1..128

    const float* Kp = K + (size_t)(b * SEQ + jstart) * DMODEL + h * HDIM + lane;
    const float* Vp = V + (size_t)(b * SEQ + jstart) * DMODEL + h * HDIM + lane;

    float s_a = -INFINITY, s_b = -INFINITY;
    for (int jj = 0; jj < nk; ++jj) {
        float part = q * Kp[(size_t)jj * DMODEL];
#pragma unroll
        for (int off = 32; off; off >>= 1) part += __shfl_xor(part, off);
        s_a = (jj == lane)      ? part : s_a;
        s_b = (jj == lane + 64) ? part : s_b;
    }

    float m = fmaxf(s_a, s_b);
#pragma unroll
    for (int off = 32; off; off >>= 1) m = fmaxf(m, __shfl_xor(m, off));

    float p_a = expf(s_a - m);   // exp(-inf) = 0 handles invalid slots
    float p_b = expf(s_b - m);
    float sum = p_a + p_b;
#pragma unroll
    for (int off = 32; off; off >>= 1) sum += __shfl_xor(sum, off);
    float inv = 1.0f / sum;

    float acc = 0.0f;
    for (int jj = 0; jj < nk; ++jj) {
        float psel = (jj < 64) ? p_a : p_b;   // uniform select
        float p = __shfl(psel, jj & 63);
        acc += p * Vp[(size_t)jj * DMODEL];
    }
    O[base + lane] = acc * inv;
}

// ---------------------------------------------------------------------------
extern "C" void kernel_launch(void* const* d_in, const int* in_sizes, int n_in,
                              void* d_out, int out_size, void* d_ws, size_t ws_size,
                              hipStream_t stream)
{
    const float* X  = (const float*)d_in[0];   // query [B,T,D]
    const float* Wq = (const float*)d_in[1];
    const float* Wk = (const float*)d_in[2];
    const float* Wv = (const float*)d_in[3];
    const float* Wo = (const float*)d_in[4];
    const float* bo = (const float*)d_in[5];
    float* out = (float*)d_out;

    const size_t mat = (size_t)ROWS * DMODEL;   // 4096*1024 floats
    float* Qb = (float*)d_ws;          // ws usage: 4 * 16.8 MB = 67 MB
    float* Kb = Qb + mat;
    float* Vb = Kb + mat;
    float* Ab = Vb + mat;

    // 1. QKV projections (one launch, z selects weight)
    {
        dim3 grid(DMODEL / 64, ROWS / 64, 3);
        gemm_qkv<<<grid, 256, 0, stream>>>(X, Wq, Wk, Wv, Qb, Kb, Vb);
    }

    // 2. RoPE on Q and K in place
    {
        int total = ROWS * NHEADS * 32;
        rope_kernel<<<(total + 255) / 256, 256, 0, stream>>>(Qb, Kb);
    }

    // 3. Sliding-window attention
    {
        dim3 grid(SEQ, NHEADS, BATCH);
        attn_kernel<<<grid, 64, 0, stream>>>(Qb, Kb, Vb, Ab);
    }

    // 4. Output projection + bias
    {
        dim3 grid(DMODEL / 64, ROWS / 64, 1);
        gemm_out<<<grid, 256, 0, stream>>>(Ab, Wo, bo, out);
    }
}

// Round 2
// 318.284 us; speedup vs baseline: 4.4822x; 4.4822x over previous
//
#include <hip/hip_runtime.h>

// Problem constants (MultiAttention_61340722921598)
#define BATCH 2
#define SEQ   2048
#define DMODEL 1024
#define NHEADS 16
#define HDIM   64
#define WINDOW 128
#define ROWS  (BATCH * SEQ)          // 4096

typedef __bf16 bf16x8 __attribute__((ext_vector_type(8)));
typedef __bf16 bf16x4 __attribute__((ext_vector_type(4)));
typedef float  f32x4  __attribute__((ext_vector_type(4)));

// ---------------------------------------------------------------------------
// Convert fp32 X and 4 weight matrices to bf16 workspace buffers.
// idx space: [0, 1M) float4-groups of X, then [1M, 2M) groups of Wq|Wk|Wv|Wo.
// ---------------------------------------------------------------------------
__global__ __launch_bounds__(256) void convert_bf16(
    const float* __restrict__ X,
    const float* __restrict__ Wq, const float* __restrict__ Wk,
    const float* __restrict__ Wv, const float* __restrict__ Wo,
    __bf16* __restrict__ Xbf, __bf16* __restrict__ Wbf)
{
    const int XN = ROWS * DMODEL / 4;     // 1M groups
    const int WN = DMODEL * DMODEL / 4;   // 256K groups per W
    int idx = blockIdx.x * blockDim.x + threadIdx.x;
    if (idx >= XN + 4 * WN) return;

    const float* src;
    __bf16* dst;
    if (idx < XN) {
        src = X + (size_t)idx * 4;
        dst = Xbf + (size_t)idx * 4;
    } else {
        int rel = idx - XN;
        int w = rel / WN;
        int off = rel - w * WN;
        const float* Wp = (w == 0) ? Wq : (w == 1) ? Wk : (w == 2) ? Wv : Wo;
        src = Wp + (size_t)off * 4;
        dst = Wbf + (size_t)rel * 4;
    }
    float4 v = *(const float4*)src;
    bf16x4 o;
    o[0] = (__bf16)v.x; o[1] = (__bf16)v.y; o[2] = (__bf16)v.z; o[3] = (__bf16)v.w;
    *(bf16x4*)dst = o;
}

// ---------------------------------------------------------------------------
// bf16 MFMA GEMM: C[m][n] = sum_k A[m][k] * B[n][k]   (both row-major, bf16)
// 128x128 tile, BK=32, 256 threads = 4 waves (2x2), each wave 64x64 via 4x4
// grid of 16x16x32 MFMA tiles. fp32 accumulate. Optional fp32-out+bias or
// bf16-out epilogue.
// A-frag/B-frag layout (verified m89/m120): elem[row = lane&15][k = (lane>>4)*8 + j]
// C/D layout: col = lane&15, row = (lane>>4)*4 + reg.
// ---------------------------------------------------------------------------
#define LDK 40   // padded LDS row length (bf16 elems); 80B rows keep 16B align

__device__ __forceinline__ void gemm_mfma_body(
    const __bf16* __restrict__ A, const __bf16* __restrict__ B,
    float* __restrict__ Cf, __bf16* __restrict__ Cb,
    const float* __restrict__ bias,
    int N, int K, int m0, int n0)
{
    __shared__ __bf16 As[128 * LDK];
    __shared__ __bf16 Bs[128 * LDK];

    const int tid  = threadIdx.x;
    const int lane = tid & 63;
    const int wv   = tid >> 6;
    const int wrow = (wv >> 1) * 64;
    const int wcol = (wv & 1) * 64;

    const int srow  = tid >> 2;        // 0..63 staging row
    const int skoff = (tid & 3) * 8;   // 0,8,16,24 (bf16 elems)

    const int frow = lane & 15;
    const int fk   = (lane >> 4) * 8;

    f32x4 acc[4][4];
#pragma unroll
    for (int i = 0; i < 4; ++i)
#pragma unroll
        for (int j = 0; j < 4; ++j) {
            acc[i][j][0] = 0.f; acc[i][j][1] = 0.f;
            acc[i][j][2] = 0.f; acc[i][j][3] = 0.f;
        }

    for (int k0 = 0; k0 < K; k0 += 32) {
        bf16x8 av0 = *(const bf16x8*)(A + (size_t)(m0 + srow) * K + k0 + skoff);
        bf16x8 av1 = *(const bf16x8*)(A + (size_t)(m0 + 64 + srow) * K + k0 + skoff);
        bf16x8 bv0 = *(const bf16x8*)(B + (size_t)(n0 + srow) * K + k0 + skoff);
        bf16x8 bv1 = *(const bf16x8*)(B + (size_t)(n0 + 64 + srow) * K + k0 + skoff);
        __syncthreads();   // previous iter's LDS reads complete
        *(bf16x8*)(As + srow * LDK + skoff) = av0;
        *(bf16x8*)(As + (64 + srow) * LDK + skoff) = av1;
        *(bf16x8*)(Bs + srow * LDK + skoff) = bv0;
        *(bf16x8*)(Bs + (64 + srow) * LDK + skoff) = bv1;
        __syncthreads();

        bf16x8 afr[4], bfr[4];
#pragma unroll
        for (int i = 0; i < 4; ++i)
            afr[i] = *(const bf16x8*)(As + (wrow + i * 16 + frow) * LDK + fk);
#pragma unroll
        for (int j = 0; j < 4; ++j)
            bfr[j] = *(const bf16x8*)(Bs + (wcol + j * 16 + frow) * LDK + fk);
#pragma unroll
        for (int i = 0; i < 4; ++i)
#pragma unroll
            for (int j = 0; j < 4; ++j)
                acc[i][j] = __builtin_amdgcn_mfma_f32_16x16x32_bf16(
                    afr[i], bfr[j], acc[i][j], 0, 0, 0);
    }

#pragma unroll
    for (int i = 0; i < 4; ++i) {
#pragma unroll
        for (int j = 0; j < 4; ++j) {
#pragma unroll
            for (int r = 0; r < 4; ++r) {
                int row = m0 + wrow + i * 16 + (lane >> 4) * 4 + r;
                int col = n0 + wcol + j * 16 + (lane & 15);
                float v = acc[i][j][r];
                if (bias) v += bias[col];
                if (Cf) Cf[(size_t)row * N + col] = v;
                else    Cb[(size_t)row * N + col] = (__bf16)v;
            }
        }
    }
}

__global__ __launch_bounds__(256) void gemm_qkv_bf(
    const __bf16* __restrict__ X, const __bf16* __restrict__ Wbf,
    float* __restrict__ Qf, float* __restrict__ Kf, float* __restrict__ Vf)
{
    const __bf16* W = Wbf + (size_t)blockIdx.z * (DMODEL * DMODEL);
    float* C = (blockIdx.z == 0) ? Qf : (blockIdx.z == 1) ? Kf : Vf;
    gemm_mfma_body(X, W, C, nullptr, nullptr, DMODEL, DMODEL,
                   blockIdx.y * 128, blockIdx.x * 128);
}

__global__ __launch_bounds__(256) void gemm_out_bf(
    const __bf16* __restrict__ Abf, const __bf16* __restrict__ Wo,
    const float* __restrict__ bias, float* __restrict__ out)
{
    gemm_mfma_body(Abf, Wo, out, nullptr, bias, DMODEL, DMODEL,
                   blockIdx.y * 128, blockIdx.x * 128);
}

// ---------------------------------------------------------------------------
// RoPE in place on fp32 Q, K (same as round-1 verified version).
// ---------------------------------------------------------------------------
__global__ void rope_kernel(float* __restrict__ Q, float* __restrict__ K)
{
    int idx = blockIdx.x * blockDim.x + threadIdx.x;
    if (idx >= ROWS * NHEADS * 32) return;
    int d   = idx & 31;
    int h   = (idx >> 5) & 15;
    int row = idx >> 9;
    int t   = row & (SEQ - 1);

    float inv = expf(-(float)d * 0.28782313662425572f);  // ln(10000)/32
    float ang = (float)t * inv;
    float s, c;
    sincosf(ang, &s, &c);

    size_t i0 = (size_t)row * DMODEL + h * HDIM + d;
    size_t i1 = i0 + 32;

    float q0 = Q[i0], q1 = Q[i1];
    Q[i0] = q0 * c - q1 * s;
    Q[i1] = q1 * c + q0 * s;

    float k0 = K[i0], k1 = K[i1];
    K[i0] = k0 * c - k1 * s;
    K[i1] = k1 * c + k0 * s;
}

// ---------------------------------------------------------------------------
// Sliding-window attention, LDS-tiled. One 256-thread block per
// (b, h, 64 q-rows). Keys j in [q0-128, q0+63] (192 rows) staged once:
//   Kt: bf16 [d=64][j=JTP]  (transposed -> lane=j reads contiguous)
//   Vs: bf16 [j=192][d=64]  (natural  -> lane=d reads contiguous)
//   Qs: bf16 [r=64][d=64]   (broadcast reads)
// Wave w handles rows r = w*16 .. w*16+15 sequentially. Per row:
//   phase1: 128 valid keys as two 64-lane chunks (j = r+1+lane, r+65+lane),
//           dense FMA over d; mask jg<0; butterfly max/sum; normalized p
//           stored to per-wave Sb slice (wave-synchronous LDS).
//   phase2: lane=d, 128 FMA over j reading Sb broadcast + Vs.
// ---------------------------------------------------------------------------
#define QTILE 64
#define JT    192
#define JTP   194   // pad: row stride 388B -> odd word stride, kills store conflicts

__global__ __launch_bounds__(256) void attn_fused(
    const float* __restrict__ Qf, const float* __restrict__ Kf,
    const float* __restrict__ Vf, __bf16* __restrict__ Abf)
{
    __shared__ __bf16 Kt[64 * JTP];     // ~24.3 KB
    __shared__ __bf16 Vs[JT * 64];      // 24 KB
    __shared__ __bf16 Qs[QTILE * 64];   // 8 KB
    __shared__ float  Sb[4 * JT];       // 3 KB   (total ~59.3 KB < 64 KB)

    const int tid  = threadIdx.x;
    const int lane = tid & 63;
    const int wv   = tid >> 6;
    const int q0   = blockIdx.x * QTILE;
    const int h    = blockIdx.y;
    const int b    = blockIdx.z;
    const int jbase = q0 - 128;

    const size_t hoff = (size_t)h * HDIM;

    // ---- stage K (transposed) and V
    for (int it = 0; it < 12; ++it) {
        int idx = tid + it * 256;          // 0..3071
        int jj = idx >> 4;                 // 0..191
        int dq = (idx & 15) * 4;           // 0..60
        int jg = jbase + jj;
        int jc = jg < 0 ? 0 : jg;          // clamp; masked later
        const float4 kv = *(const float4*)(Kf + ((size_t)(b * SEQ) + jc) * DMODEL + hoff + dq);
        const float4 vv = *(const float4*)(Vf + ((size_t)(b * SEQ) + jc) * DMODEL + hoff + dq);
        Kt[(dq + 0) * JTP + jj] = (__bf16)kv.x;
        Kt[(dq + 1) * JTP + jj] = (__bf16)kv.y;
        Kt[(dq + 2) * JTP + jj] = (__bf16)kv.z;
        Kt[(dq + 3) * JTP + jj] = (__bf16)kv.w;
        bf16x4 vo;
        vo[0] = (__bf16)vv.x; vo[1] = (__bf16)vv.y;
        vo[2] = (__bf16)vv.z; vo[3] = (__bf16)vv.w;
        *(bf16x4*)(Vs + jj * 64 + dq) = vo;
    }
    // ---- stage Q (pre-scaled by 1/sqrt(Dh))
    for (int it = 0; it < 4; ++it) {
        int idx = tid + it * 256;          // 0..1023
        int r  = idx >> 4;
        int dq = (idx & 15) * 4;
        float4 qv = *(const float4*)(Qf + ((size_t)(b * SEQ) + q0 + r) * DMODEL + hoff + dq);
        bf16x4 qo;
        qo[0] = (__bf16)(qv.x * 0.125f); qo[1] = (__bf16)(qv.y * 0.125f);
        qo[2] = (__bf16)(qv.z * 0.125f); qo[3] = (__bf16)(qv.w * 0.125f);
        *(bf16x4*)(Qs + r * 64 + dq) = qo;
    }
    __syncthreads();

    float* mySb = Sb + wv * JT;

    for (int rr = 0; rr < 16; ++rr) {
        const int r = wv * 16 + rr;
        const int t = q0 + r;
        const int jA = r + 1 + lane;       // tile coords of the 128-key window
        const int jB = r + 65 + lane;

        // phase 1: scores
        float sA = 0.f, sB = 0.f;
        const __bf16* qrow = Qs + r * 64;
#pragma unroll 8
        for (int d = 0; d < 64; ++d) {
            float qd = (float)qrow[d];
            const __bf16* krow = Kt + d * JTP;
            sA += qd * (float)krow[jA];
            sB += qd * (float)krow[jB];
        }
        // mask: jg must be >= 0 (upper/lower window bounds hold by construction)
        int jgA = jbase + jA;
        int jgB = jbase + jB;
        sA = (jgA >= 0) ? sA : -INFINITY;
        sB = (jgB >= 0) ? sB : -INFINITY;

        float m = fmaxf(sA, sB);
#pragma unroll
        for (int off = 32; off; off >>= 1) m = fmaxf(m, __shfl_xor(m, off));
        float pA = __expf(sA - m);
        float pB = __expf(sB - m);
        float sum = pA + pB;
#pragma unroll
        for (int off = 32; off; off >>= 1) sum += __shfl_xor(sum, off);
        float inv = 1.0f / sum;

        mySb[jA] = pA * inv;
        mySb[jB] = pB * inv;
        asm volatile("" ::: "memory");
        __builtin_amdgcn_s_waitcnt(0);   // wave-synchronous LDS: drain writes

        // phase 2: out[d=lane] = sum_j p_j * V[j][d]
        float o = 0.f;
#pragma unroll 8
        for (int jj = 1; jj <= 128; ++jj) {
            int j = r + jj;
            o += mySb[j] * (float)Vs[j * 64 + lane];
        }
        Abf[((size_t)(b * SEQ) + t) * DMODEL + hoff + lane] = (__bf16)o;
        asm volatile("" ::: "memory");
        __builtin_amdgcn_s_waitcnt(0);   // reads drained before next-row overwrite
    }
}

// ---------------------------------------------------------------------------
extern "C" void kernel_launch(void* const* d_in, const int* in_sizes, int n_in,
                              void* d_out, int out_size, void* d_ws, size_t ws_size,
                              hipStream_t stream)
{
    const float* X  = (const float*)d_in[0];
    const float* Wq = (const float*)d_in[1];
    const float* Wk = (const float*)d_in[2];
    const float* Wv = (const float*)d_in[3];
    const float* Wo = (const float*)d_in[4];
    const float* bo = (const float*)d_in[5];
    float* out = (float*)d_out;

    const size_t MB = 1ull << 20;
    __bf16* Xbf = (__bf16*)d_ws;                        // 8 MB; reused as Abf later
    __bf16* Wbf = (__bf16*)((char*)d_ws + 8 * MB);      // 8 MB (Wq|Wk|Wv|Wo)
    float*  Qf  = (float*)((char*)d_ws + 16 * MB);      // 16 MB
    float*  Kf  = (float*)((char*)d_ws + 32 * MB);      // 16 MB
    float*  Vf  = (float*)((char*)d_ws + 48 * MB);      // 16 MB (total 64 MB)
    __bf16* Abf = Xbf;   // X no longer needed after QKV projection

    // 1. fp32 -> bf16 conversion of X and weights
    {
        int groups = (ROWS * DMODEL + 4 * DMODEL * DMODEL) / 4;  // 2M
        convert_bf16<<<(groups + 255) / 256, 256, 0, stream>>>(
            X, Wq, Wk, Wv, Wo, Xbf, Wbf);
    }
    // 2. QKV projections (bf16 MFMA, fp32 out)
    {
        dim3 grid(DMODEL / 128, ROWS / 128, 3);
        gemm_qkv_bf<<<grid, 256, 0, stream>>>(Xbf, Wbf, Qf, Kf, Vf);
    }
    // 3. RoPE in place (fp32)
    {
        int total = ROWS * NHEADS * 32;
        rope_kernel<<<(total + 255) / 256, 256, 0, stream>>>(Qf, Kf);
    }
    // 4. Sliding-window attention -> bf16
    {
        dim3 grid(SEQ / QTILE, NHEADS, BATCH);
        attn_fused<<<grid, 256, 0, stream>>>(Qf, Kf, Vf, Abf);
    }
    // 5. Output projection + bias (bf16 MFMA, fp32 out)
    {
        dim3 grid(DMODEL / 128, ROWS / 128, 1);
        gemm_out_bf<<<grid, 256, 0, stream>>>(Abf, Wbf + 3ull * DMODEL * DMODEL, bo, out);
    }
}

// Round 3
// 188.454 us; speedup vs baseline: 7.5700x; 1.6889x over previous
//
#include <hip/hip_runtime.h>

// Problem constants (MultiAttention_61340722921598)
#define BATCH 2
#define SEQ   2048
#define DMODEL 1024
#define NHEADS 16
#define HDIM   64
#define WINDOW 128
#define ROWS  (BATCH * SEQ)          // 4096

typedef __bf16 bf16x8 __attribute__((ext_vector_type(8)));
typedef __bf16 bf16x4 __attribute__((ext_vector_type(4)));
typedef float  f32x4  __attribute__((ext_vector_type(4)));

// ---------------------------------------------------------------------------
// fp32 -> bf16 conversion of X and the 4 weight matrices.
// ---------------------------------------------------------------------------
__global__ __launch_bounds__(256) void convert_bf16(
    const float* __restrict__ X,
    const float* __restrict__ Wq, const float* __restrict__ Wk,
    const float* __restrict__ Wv, const float* __restrict__ Wo,
    __bf16* __restrict__ Xbf, __bf16* __restrict__ Wbf)
{
    const int XN = ROWS * DMODEL / 4;     // 1M groups
    const int WN = DMODEL * DMODEL / 4;   // 256K groups per W
    int idx = blockIdx.x * blockDim.x + threadIdx.x;
    if (idx >= XN + 4 * WN) return;

    const float* src;
    __bf16* dst;
    if (idx < XN) {
        src = X + (size_t)idx * 4;
        dst = Xbf + (size_t)idx * 4;
    } else {
        int rel = idx - XN;
        int w = rel / WN;
        int off = rel - w * WN;
        const float* Wp = (w == 0) ? Wq : (w == 1) ? Wk : (w == 2) ? Wv : Wo;
        src = Wp + (size_t)off * 4;
        dst = Wbf + (size_t)rel * 4;
    }
    float4 v = *(const float4*)src;
    bf16x4 o;
    o[0] = (__bf16)v.x; o[1] = (__bf16)v.y; o[2] = (__bf16)v.z; o[3] = (__bf16)v.w;
    *(bf16x4*)dst = o;
}

// ---------------------------------------------------------------------------
// RoPE cos/sin table: [t][d<32], exact libm sincos (matches fp32 reference).
// ---------------------------------------------------------------------------
__global__ __launch_bounds__(256) void rope_table(float* __restrict__ ct,
                                                  float* __restrict__ st)
{
    int idx = blockIdx.x * blockDim.x + threadIdx.x;
    if (idx >= SEQ * 32) return;
    int t = idx >> 5, d = idx & 31;
    float ang = (float)t * expf(-(float)d * 0.28782313662425572f); // ln(1e4)/32
    float s, c;
    sincosf(ang, &s, &c);
    ct[idx] = c; st[idx] = s;
}

// ---------------------------------------------------------------------------
// bf16 MFMA GEMM: C[m][n] = sum_k A[m][k] * B[n][k]   (both row-major, bf16)
// 128x128 tile, BK=32, 256 threads = 4 waves (2x2), 4x4 grid of 16x16x32
// MFMA per wave. Epilogue modes:
//   0 = Q: RoPE + 1/sqrt(Dh) scale, bf16 out
//   1 = K: RoPE, bf16 out
//   2 = V: bf16 out
//   3 = fp32 out + bias (output projection)
// A/B-frag: elem[row=lane&15][k=(lane>>4)*8+j]; C/D: col=lane&15,
// row=(lane>>4)*4+reg (verified m89).
// ---------------------------------------------------------------------------
#define LDK 40   // padded LDS row length (bf16)

__device__ __forceinline__ void gemm_mfma_body(
    const __bf16* __restrict__ A, const __bf16* __restrict__ B,
    void* __restrict__ Cout, const float* __restrict__ bias,
    const float* __restrict__ ct, const float* __restrict__ st,
    int mode, int N, int K, int m0, int n0)
{
    __shared__ __bf16 As[128 * LDK];
    __shared__ __bf16 Bs[128 * LDK];

    const int tid  = threadIdx.x;
    const int lane = tid & 63;
    const int wv   = tid >> 6;
    const int wrow = (wv >> 1) * 64;
    const int wcol = (wv & 1) * 64;

    const int srow  = tid >> 2;
    const int skoff = (tid & 3) * 8;

    const int frow = lane & 15;
    const int fk   = (lane >> 4) * 8;

    f32x4 acc[4][4];
#pragma unroll
    for (int i = 0; i < 4; ++i)
#pragma unroll
        for (int j = 0; j < 4; ++j) {
            acc[i][j][0] = 0.f; acc[i][j][1] = 0.f;
            acc[i][j][2] = 0.f; acc[i][j][3] = 0.f;
        }

    for (int k0 = 0; k0 < K; k0 += 32) {
        bf16x8 av0 = *(const bf16x8*)(A + (size_t)(m0 + srow) * K + k0 + skoff);
        bf16x8 av1 = *(const bf16x8*)(A + (size_t)(m0 + 64 + srow) * K + k0 + skoff);
        bf16x8 bv0 = *(const bf16x8*)(B + (size_t)(n0 + srow) * K + k0 + skoff);
        bf16x8 bv1 = *(const bf16x8*)(B + (size_t)(n0 + 64 + srow) * K + k0 + skoff);
        __syncthreads();
        *(bf16x8*)(As + srow * LDK + skoff) = av0;
        *(bf16x8*)(As + (64 + srow) * LDK + skoff) = av1;
        *(bf16x8*)(Bs + srow * LDK + skoff) = bv0;
        *(bf16x8*)(Bs + (64 + srow) * LDK + skoff) = bv1;
        __syncthreads();

        bf16x8 afr[4], bfr[4];
#pragma unroll
        for (int i = 0; i < 4; ++i)
            afr[i] = *(const bf16x8*)(As + (wrow + i * 16 + frow) * LDK + fk);
#pragma unroll
        for (int j = 0; j < 4; ++j)
            bfr[j] = *(const bf16x8*)(Bs + (wcol + j * 16 + frow) * LDK + fk);
#pragma unroll
        for (int i = 0; i < 4; ++i)
#pragma unroll
            for (int j = 0; j < 4; ++j)
                acc[i][j] = __builtin_amdgcn_mfma_f32_16x16x32_bf16(
                    afr[i], bfr[j], acc[i][j], 0, 0, 0);
    }

#pragma unroll
    for (int i = 0; i < 4; ++i) {
#pragma unroll
        for (int r = 0; r < 4; ++r) {
            int row = m0 + wrow + i * 16 + (lane >> 4) * 4 + r;
            if (mode <= 1) {
                // RoPE: pairs (d, d+32) live in (acc[i][j], acc[i][j+2]), d=j*16+(lane&15)<32
                int t = row & (SEQ - 1);
#pragma unroll
                for (int j = 0; j < 2; ++j) {
                    int dd = j * 16 + (lane & 15);
                    float c = ct[t * 32 + dd];
                    float s = st[t * 32 + dd];
                    float v0 = acc[i][j][r], v1 = acc[i][j + 2][r];
                    float n0v = v0 * c - v1 * s;
                    float n1v = v1 * c + v0 * s;
                    if (mode == 0) { n0v *= 0.125f; n1v *= 0.125f; }
                    acc[i][j][r] = n0v; acc[i][j + 2][r] = n1v;
                }
            }
#pragma unroll
            for (int j = 0; j < 4; ++j) {
                int col = n0 + wcol + j * 16 + (lane & 15);
                float v = acc[i][j][r];
                if (mode == 3)
                    ((float*)Cout)[(size_t)row * N + col] = v + bias[col];
                else
                    ((__bf16*)Cout)[(size_t)row * N + col] = (__bf16)v;
            }
        }
    }
}

__global__ __launch_bounds__(256) void gemm_qkv_bf(
    const __bf16* __restrict__ X, const __bf16* __restrict__ Wbf,
    __bf16* __restrict__ Qb, __bf16* __restrict__ Kb, __bf16* __restrict__ Vb,
    const float* __restrict__ ct, const float* __restrict__ st)
{
    const int z = blockIdx.z;
    const __bf16* W = Wbf + (size_t)z * (DMODEL * DMODEL);
    __bf16* C = (z == 0) ? Qb : (z == 1) ? Kb : Vb;
    gemm_mfma_body(X, W, C, nullptr, ct, st, z, DMODEL, DMODEL,
                   blockIdx.y * 128, blockIdx.x * 128);
}

__global__ __launch_bounds__(256) void gemm_out_bf(
    const __bf16* __restrict__ Abf, const __bf16* __restrict__ Wo,
    const float* __restrict__ bias, float* __restrict__ out)
{
    gemm_mfma_body(Abf, Wo, out, bias, nullptr, nullptr, 3, DMODEL, DMODEL,
                   blockIdx.y * 128, blockIdx.x * 128);
}

// ---------------------------------------------------------------------------
// MFMA sliding-window attention. One 256-thread block per (b, h, 64 q-rows).
// Key window jt in [0,192) <-> global j = q0-128+jt. Wave w owns q-rows
// 16w..16w+15 (one 16-row MFMA m-tile).
//   S:  4 waves x 9 col-tiles x 2 k-steps of mfma_16x16x32 (Q A-frags direct
//       from global; K B-frags from LDS Ks).
//   softmax: mask + per-row butterfly max/sum on C-layout frags (regs only).
//   P:  normalized, bf16, written to per-wave LDS slice (aliases Ks after
//       barrier), re-read as A-frags (m120 round-trip pattern).
//   PV: 5 k-steps x 4 out-tiles vs transposed V (Vt). Cols jt>=192 zeroed.
// Pads: 2-way bank conflicts max on all fragment reads (free, m136).
// ---------------------------------------------------------------------------
#define QTILE 64
#define KPAD  72    // Ks row (bf16): 36 words/row -> 8 distinct bank offsets
#define VPAD  216   // Vt row: 108 words -> 8 distinct offsets
#define PPAD  168   // Ps row: 84 words -> 8 distinct offsets

__global__ __launch_bounds__(256) void attn_mfma(
    const __bf16* __restrict__ Qb, const __bf16* __restrict__ Kb,
    const __bf16* __restrict__ Vb, __bf16* __restrict__ Abf)
{
    __shared__ __bf16 KsPs[192 * KPAD];  // 27648 B; Ks, then reused as Ps
    __shared__ __bf16 Vt[64 * VPAD];     // 27648 B  (total 55296 B)

    const int tid  = threadIdx.x;
    const int lane = tid & 63;
    const int wv   = tid >> 6;
    const int q0   = blockIdx.x * QTILE;
    const int h    = blockIdx.y;
    const int b    = blockIdx.z;
    const int jbase = q0 - 128;
    const size_t hoff = (size_t)h * HDIM;
    const int nloc  = lane & 15;
    const int mbase = (lane >> 4) * 4;
    const int fk    = (lane >> 4) * 8;

    const __bf16* Kg = Kb + (size_t)(b * SEQ) * DMODEL + hoff;
    const __bf16* Vg = Vb + (size_t)(b * SEQ) * DMODEL + hoff;

    // ---- stage Ks (natural) + Vt (transposed)
#pragma unroll
    for (int it = 0; it < 6; ++it) {
        int idx = tid + it * 256;          // 0..1535
        int jt = idx >> 3;                 // 0..191
        int dq = (idx & 7) * 8;
        int jg = jbase + jt;
        int jc = jg < 0 ? 0 : jg;          // clamp; masked via p=0 later
        bf16x8 kv = *(const bf16x8*)(Kg + (size_t)jc * DMODEL + dq);
        bf16x8 vv = *(const bf16x8*)(Vg + (size_t)jc * DMODEL + dq);
        *(bf16x8*)(KsPs + jt * KPAD + dq) = kv;
#pragma unroll
        for (int e = 0; e < 8; ++e) Vt[(dq + e) * VPAD + jt] = vv[e];
    }
    // zero Vt cols [192,208) (read by PV k-steps, must not be NaN garbage)
#pragma unroll
    for (int it = 0; it < 4; ++it) {
        int idx = tid + it * 256;          // 0..1023
        int d = idx >> 4, c = idx & 15;
        Vt[d * VPAD + 192 + c] = (__bf16)0.0f;
    }
    __syncthreads();

    // ---- Q A-frags direct from global (rows q0+16w+nloc, 16B/lane)
    const __bf16* Qg = Qb + (size_t)(b * SEQ + q0 + 16 * wv + nloc) * DMODEL + hoff + fk;
    bf16x8 qfr0 = *(const bf16x8*)(Qg);
    bf16x8 qfr1 = *(const bf16x8*)(Qg + 32);

    // ---- S = Q K^T over 9 column tiles
    f32x4 s[9];
#pragma unroll
    for (int c = 0; c < 9; ++c) {
        const __bf16* kp = KsPs + (size_t)(16 * (wv + c) + nloc) * KPAD + fk;
        bf16x8 k0 = *(const bf16x8*)kp;
        bf16x8 k1 = *(const bf16x8*)(kp + 32);
        f32x4 z; z[0] = 0.f; z[1] = 0.f; z[2] = 0.f; z[3] = 0.f;
        z = __builtin_amdgcn_mfma_f32_16x16x32_bf16(qfr0, k0, z, 0, 0, 0);
        z = __builtin_amdgcn_mfma_f32_16x16x32_bf16(qfr1, k1, z, 0, 0, 0);
        s[c] = z;
    }
    __syncthreads();   // all waves done reading Ks; safe to alias with Ps

    // ---- mask + softmax (registers only); then write normalized P (bf16)
    float inv_row[4];
#pragma unroll
    for (int r = 0; r < 4; ++r) {
        int rl = 16 * wv + mbase + r;
        float mx = -INFINITY;
#pragma unroll
        for (int c = 0; c < 9; ++c) {
            int jt = 16 * (wv + c) + nloc;
            bool valid = (jt >= rl + 1) && (jt <= rl + 128) && (jbase + jt >= 0);
            float sv = valid ? s[c][r] : -INFINITY;
            s[c][r] = sv;
            mx = fmaxf(mx, sv);
        }
#pragma unroll
        for (int off = 8; off; off >>= 1) mx = fmaxf(mx, __shfl_xor(mx, off));
        float sum = 0.f;
#pragma unroll
        for (int c = 0; c < 9; ++c) {
            float p = __expf(s[c][r] - mx);
            s[c][r] = p;
            sum += p;
        }
#pragma unroll
        for (int off = 8; off; off >>= 1) sum += __shfl_xor(sum, off);
        inv_row[r] = 1.0f / sum;
    }

    __bf16* myP = KsPs + (size_t)wv * 16 * PPAD;
#pragma unroll
    for (int c = 0; c < 9; ++c)
#pragma unroll
        for (int r = 0; r < 4; ++r)
            myP[(mbase + r) * PPAD + 16 * c + nloc] = (__bf16)(s[c][r] * inv_row[r]);
#pragma unroll
    for (int r = 0; r < 4; ++r)       // zero P cols [144,160)
        myP[(mbase + r) * PPAD + 144 + nloc] = (__bf16)0.0f;

    asm volatile("" ::: "memory");
    __builtin_amdgcn_s_waitcnt(0);    // wave-local LDS write->read ordering

    // ---- O = P V  (5 k-steps of 32 keys, 4 d-tiles)
    f32x4 o[4];
#pragma unroll
    for (int j = 0; j < 4; ++j) { o[j][0] = 0.f; o[j][1] = 0.f; o[j][2] = 0.f; o[j][3] = 0.f; }
#pragma unroll
    for (int stp = 0; stp < 5; ++stp) {
        bf16x8 pf = *(const bf16x8*)(myP + nloc * PPAD + 32 * stp + fk);
#pragma unroll
        for (int j = 0; j < 4; ++j) {
            bf16x8 vf = *(const bf16x8*)(Vt + (size_t)(16 * j + nloc) * VPAD
                                         + 16 * wv + 32 * stp + fk);
            o[j] = __builtin_amdgcn_mfma_f32_16x16x32_bf16(pf, vf, o[j], 0, 0, 0);
        }
    }

    // ---- epilogue: C-layout -> global bf16
    __bf16* Og = Abf + (size_t)(b * SEQ + q0 + 16 * wv) * DMODEL + hoff;
#pragma unroll
    for (int j = 0; j < 4; ++j)
#pragma unroll
        for (int r = 0; r < 4; ++r)
            Og[(size_t)(mbase + r) * DMODEL + 16 * j + nloc] = (__bf16)o[j][r];
}

// ---------------------------------------------------------------------------
extern "C" void kernel_launch(void* const* d_in, const int* in_sizes, int n_in,
                              void* d_out, int out_size, void* d_ws, size_t ws_size,
                              hipStream_t stream)
{
    const float* X  = (const float*)d_in[0];
    const float* Wq = (const float*)d_in[1];
    const float* Wk = (const float*)d_in[2];
    const float* Wv = (const float*)d_in[3];
    const float* Wo = (const float*)d_in[4];
    const float* bo = (const float*)d_in[5];
    float* out = (float*)d_out;

    const size_t MB = 1ull << 20;
    __bf16* Xbf = (__bf16*)d_ws;                        // 8 MB; reused as Abf
    __bf16* Wbf = (__bf16*)((char*)d_ws + 8 * MB);      // 8 MB (Wq|Wk|Wv|Wo)
    __bf16* Qb  = (__bf16*)((char*)d_ws + 16 * MB);     // 8 MB
    __bf16* Kb  = (__bf16*)((char*)d_ws + 24 * MB);     // 8 MB
    __bf16* Vb  = (__bf16*)((char*)d_ws + 32 * MB);     // 8 MB
    float*  ctab = (float*)((char*)d_ws + 40 * MB);     // 256 KB
    float*  stab = (float*)((char*)d_ws + 41 * MB);     // 256 KB
    __bf16* Abf = Xbf;   // X dead after QKV projection

    // 1. fp32 -> bf16 conversion
    {
        int groups = (ROWS * DMODEL + 4 * DMODEL * DMODEL) / 4;
        convert_bf16<<<(groups + 255) / 256, 256, 0, stream>>>(
            X, Wq, Wk, Wv, Wo, Xbf, Wbf);
    }
    // 2. RoPE cos/sin table
    {
        rope_table<<<(SEQ * 32 + 255) / 256, 256, 0, stream>>>(ctab, stab);
    }
    // 3. QKV projections with fused RoPE (+Q scale), bf16 out
    {
        dim3 grid(DMODEL / 128, ROWS / 128, 3);
        gemm_qkv_bf<<<grid, 256, 0, stream>>>(Xbf, Wbf, Qb, Kb, Vb, ctab, stab);
    }
    // 4. MFMA sliding-window attention -> bf16
    {
        dim3 grid(SEQ / QTILE, NHEADS, BATCH);
        attn_mfma<<<grid, 256, 0, stream>>>(Qb, Kb, Vb, Abf);
    }
    // 5. Output projection + bias (fp32 out)
    {
        dim3 grid(DMODEL / 128, ROWS / 128, 1);
        gemm_out_bf<<<grid, 256, 0, stream>>>(Abf, Wbf + 3ull * DMODEL * DMODEL, bo, out);
    }
}

// Round 4
// 184.654 us; speedup vs baseline: 7.7258x; 1.0206x over previous
//
#include <hip/hip_runtime.h>

// Problem constants (MultiAttention_61340722921598)
#define BATCH 2
#define SEQ   2048
#define DMODEL 1024
#define NHEADS 16
#define HDIM   64
#define WINDOW 128
#define ROWS  (BATCH * SEQ)          // 4096

typedef __bf16 bf16x8 __attribute__((ext_vector_type(8)));
typedef __bf16 bf16x4 __attribute__((ext_vector_type(4)));
typedef float  f32x4  __attribute__((ext_vector_type(4)));

// async global->LDS, 16B per lane; LDS dest = wave-uniform base + lane*16
__device__ __forceinline__ void async_load16(const __bf16* g, __bf16* l) {
    __builtin_amdgcn_global_load_lds(
        (const __attribute__((address_space(1))) unsigned int*)g,
        (__attribute__((address_space(3))) unsigned int*)l, 16, 0, 0);
}

// ---------------------------------------------------------------------------
// fp32 -> bf16 conversion of X and the 4 weights; tail range computes the
// RoPE cos/sin table (exact libm sincosf, matching the fp32 reference).
// ---------------------------------------------------------------------------
__global__ __launch_bounds__(256) void convert_bf16(
    const float* __restrict__ X,
    const float* __restrict__ Wq, const float* __restrict__ Wk,
    const float* __restrict__ Wv, const float* __restrict__ Wo,
    __bf16* __restrict__ Xbf, __bf16* __restrict__ Wbf,
    float* __restrict__ ct, float* __restrict__ st)
{
    const int XN = ROWS * DMODEL / 4;     // 1,048,576 groups
    const int WN = DMODEL * DMODEL / 4;   // 262,144 per W
    const int TOT = XN + 4 * WN;          // 2,097,152
    int idx = blockIdx.x * blockDim.x + threadIdx.x;

    if (idx < TOT) {
        const float* src;
        __bf16* dst;
        if (idx < XN) {
            src = X + (size_t)idx * 4;
            dst = Xbf + (size_t)idx * 4;
        } else {
            int rel = idx - XN;
            int w = rel / WN;
            int off = rel - w * WN;
            const float* Wp = (w == 0) ? Wq : (w == 1) ? Wk : (w == 2) ? Wv : Wo;
            src = Wp + (size_t)off * 4;
            dst = Wbf + (size_t)rel * 4;
        }
        float4 v = *(const float4*)src;
        bf16x4 o;
        o[0] = (__bf16)v.x; o[1] = (__bf16)v.y; o[2] = (__bf16)v.z; o[3] = (__bf16)v.w;
        *(bf16x4*)dst = o;
    } else if (idx < TOT + SEQ * 32) {
        int k = idx - TOT;
        int t = k >> 5, d = k & 31;
        float ang = (float)t * expf(-(float)d * 0.28782313662425572f); // ln(1e4)/32
        float s, c;
        sincosf(ang, &s, &c);
        ct[k] = c; st[k] = s;
    }
}

// ---------------------------------------------------------------------------
// bf16 MFMA GEMM, m97 structure: C[m][n] = sum_k A[m][k] * B[n][k].
// 128x128 tile, BK=32, 256 threads = 4 waves (2x2), 4x4 of 16x16x32 MFMA per
// wave. Staging via global_load_lds (16B/lane, 4 calls/wave/k-step) into
// unpadded 128x32 LDS tiles. Bank conflicts on fragment reads broken by an
// XOR chunk swizzle: LDS row r slot cp holds global chunk cp^((r>>1)&3)
// (applied on the *source* address per lane -> coalescing unchanged; b128
// fragment reads land 2-way per bank-quad = free, m136).
// Epilogue modes: 0=Q (RoPE+0.125 scale, bf16), 1=K (RoPE, bf16),
// 2=V (bf16), 3=fp32+bias.
// A/B-frag: elem[row=lane&15][k=(lane>>4)*8+j]; C/D: col=lane&15,
// row=(lane>>4)*4+reg (verified m89).
// ---------------------------------------------------------------------------
__device__ __forceinline__ void gemm_mfma_body(
    const __bf16* __restrict__ A, const __bf16* __restrict__ B,
    void* __restrict__ Cout, const float* __restrict__ bias,
    const float* __restrict__ ct, const float* __restrict__ st,
    int mode, int N, int K, int m0, int n0)
{
    __shared__ __bf16 As[128 * 32];   // 8 KB
    __shared__ __bf16 Bs[128 * 32];   // 8 KB

    const int tid  = threadIdx.x;
    const int lane = tid & 63;
    const int wv   = tid >> 6;
    const int wrow = (wv >> 1) * 64;
    const int wcol = (wv & 1) * 64;

    // staging map: lane -> (row16 = lane>>2, swizzled source chunk)
    const int srow = lane >> 2;
    const int schk = (lane & 3) ^ ((lane >> 3) & 3);   // (lane>>3)&3 == (row16>>1)&3
    const int rbase = 32 * wv;                          // wave covers 32 rows (2 calls)

    const __bf16* gA0 = A + (size_t)(m0 + rbase + srow) * K + 8 * schk;
    const __bf16* gA1 = gA0 + (size_t)16 * K;
    const __bf16* gB0 = B + (size_t)(n0 + rbase + srow) * K + 8 * schk;
    const __bf16* gB1 = gB0 + (size_t)16 * K;
    __bf16* lA0 = As + rbase * 32;
    __bf16* lA1 = lA0 + 16 * 32;
    __bf16* lB0 = Bs + rbase * 32;
    __bf16* lB1 = lB0 + 16 * 32;

    // fragment read map: row frow, global chunk lane>>4 at swizzled LDS slot
    const int frow = lane & 15;
    const int fsw  = 8 * ((lane >> 4) ^ ((frow >> 1) & 3));

    f32x4 acc[4][4];
#pragma unroll
    for (int i = 0; i < 4; ++i)
#pragma unroll
        for (int j = 0; j < 4; ++j) {
            acc[i][j][0] = 0.f; acc[i][j][1] = 0.f;
            acc[i][j][2] = 0.f; acc[i][j][3] = 0.f;
        }

    for (int k0 = 0; k0 < K; k0 += 32) {
        __syncthreads();                 // prior iter's LDS reads complete
        async_load16(gA0 + k0, lA0);
        async_load16(gA1 + k0, lA1);
        async_load16(gB0 + k0, lB0);
        async_load16(gB1 + k0, lB1);
        __syncthreads();                 // drains vmcnt: staging visible

        bf16x8 afr[4], bfr[4];
#pragma unroll
        for (int i = 0; i < 4; ++i)
            afr[i] = *(const bf16x8*)(As + (wrow + 16 * i + frow) * 32 + fsw);
#pragma unroll
        for (int j = 0; j < 4; ++j)
            bfr[j] = *(const bf16x8*)(Bs + (wcol + 16 * j + frow) * 32 + fsw);
#pragma unroll
        for (int i = 0; i < 4; ++i)
#pragma unroll
            for (int j = 0; j < 4; ++j)
                acc[i][j] = __builtin_amdgcn_mfma_f32_16x16x32_bf16(
                    afr[i], bfr[j], acc[i][j], 0, 0, 0);
    }

#pragma unroll
    for (int i = 0; i < 4; ++i) {
#pragma unroll
        for (int r = 0; r < 4; ++r) {
            int row = m0 + wrow + i * 16 + (lane >> 4) * 4 + r;
            if (mode <= 1) {
                // RoPE: pairs (d, d+32) live in (acc[i][j], acc[i][j+2]), d=j*16+(lane&15)<32
                int t = row & (SEQ - 1);
#pragma unroll
                for (int j = 0; j < 2; ++j) {
                    int dd = j * 16 + (lane & 15);
                    float c = ct[t * 32 + dd];
                    float s = st[t * 32 + dd];
                    float v0 = acc[i][j][r], v1 = acc[i][j + 2][r];
                    float n0v = v0 * c - v1 * s;
                    float n1v = v1 * c + v0 * s;
                    if (mode == 0) { n0v *= 0.125f; n1v *= 0.125f; }
                    acc[i][j][r] = n0v; acc[i][j + 2][r] = n1v;
                }
            }
#pragma unroll
            for (int j = 0; j < 4; ++j) {
                int col = n0 + wcol + j * 16 + (lane & 15);
                float v = acc[i][j][r];
                if (mode == 3)
                    ((float*)Cout)[(size_t)row * N + col] = v + bias[col];
                else
                    ((__bf16*)Cout)[(size_t)row * N + col] = (__bf16)v;
            }
        }
    }
}

__global__ __launch_bounds__(256) void gemm_qkv_bf(
    const __bf16* __restrict__ X, const __bf16* __restrict__ Wbf,
    __bf16* __restrict__ Qb, __bf16* __restrict__ Kb, __bf16* __restrict__ Vb,
    const float* __restrict__ ct, const float* __restrict__ st)
{
    const int z = blockIdx.z;
    const __bf16* W = Wbf + (size_t)z * (DMODEL * DMODEL);
    __bf16* C = (z == 0) ? Qb : (z == 1) ? Kb : Vb;
    gemm_mfma_body(X, W, C, nullptr, ct, st, z, DMODEL, DMODEL,
                   blockIdx.y * 128, blockIdx.x * 128);
}

__global__ __launch_bounds__(256) void gemm_out_bf(
    const __bf16* __restrict__ Abf, const __bf16* __restrict__ Wo,
    const float* __restrict__ bias, float* __restrict__ out)
{
    gemm_mfma_body(Abf, Wo, out, bias, nullptr, nullptr, 3, DMODEL, DMODEL,
                   blockIdx.y * 128, blockIdx.x * 128);
}

// ---------------------------------------------------------------------------
// MFMA sliding-window attention (verified round 3). One 256-thread block per
// (b, h, 64 q-rows); wave w owns q-rows 16w..16w+15.
// ---------------------------------------------------------------------------
#define QTILE 64
#define KPAD  72    // Ks row (bf16): 36 words/row -> 8 distinct bank offsets
#define VPAD  216   // Vt row: 108 words -> 8 distinct offsets
#define PPAD  168   // Ps row: 84 words -> 8 distinct offsets

__global__ __launch_bounds__(256) void attn_mfma(
    const __bf16* __restrict__ Qb, const __bf16* __restrict__ Kb,
    const __bf16* __restrict__ Vb, __bf16* __restrict__ Abf)
{
    __shared__ __bf16 KsPs[192 * KPAD];  // 27648 B; Ks, then reused as Ps
    __shared__ __bf16 Vt[64 * VPAD];     // 27648 B  (total 55296 B)

    const int tid  = threadIdx.x;
    const int lane = tid & 63;
    const int wv   = tid >> 6;
    const int q0   = blockIdx.x * QTILE;
    const int h    = blockIdx.y;
    const int b    = blockIdx.z;
    const int jbase = q0 - 128;
    const size_t hoff = (size_t)h * HDIM;
    const int nloc  = lane & 15;
    const int mbase = (lane >> 4) * 4;
    const int fk    = (lane >> 4) * 8;

    const __bf16* Kg = Kb + (size_t)(b * SEQ) * DMODEL + hoff;
    const __bf16* Vg = Vb + (size_t)(b * SEQ) * DMODEL + hoff;

    // ---- stage Ks (natural) + Vt (transposed)
#pragma unroll
    for (int it = 0; it < 6; ++it) {
        int idx = tid + it * 256;          // 0..1535
        int jt = idx >> 3;                 // 0..191
        int dq = (idx & 7) * 8;
        int jg = jbase + jt;
        int jc = jg < 0 ? 0 : jg;          // clamp; masked via p=0 later
        bf16x8 kv = *(const bf16x8*)(Kg + (size_t)jc * DMODEL + dq);
        bf16x8 vv = *(const bf16x8*)(Vg + (size_t)jc * DMODEL + dq);
        *(bf16x8*)(KsPs + jt * KPAD + dq) = kv;
#pragma unroll
        for (int e = 0; e < 8; ++e) Vt[(dq + e) * VPAD + jt] = vv[e];
    }
    // zero Vt cols [192,208) (read by PV k-steps; must not be garbage)
#pragma unroll
    for (int it = 0; it < 4; ++it) {
        int idx = tid + it * 256;          // 0..1023
        int d = idx >> 4, c = idx & 15;
        Vt[d * VPAD + 192 + c] = (__bf16)0.0f;
    }
    __syncthreads();

    // ---- Q A-frags direct from global
    const __bf16* Qg = Qb + (size_t)(b * SEQ + q0 + 16 * wv + nloc) * DMODEL + hoff + fk;
    bf16x8 qfr0 = *(const bf16x8*)(Qg);
    bf16x8 qfr1 = *(const bf16x8*)(Qg + 32);

    // ---- S = Q K^T over 9 column tiles
    f32x4 s[9];
#pragma unroll
    for (int c = 0; c < 9; ++c) {
        const __bf16* kp = KsPs + (size_t)(16 * (wv + c) + nloc) * KPAD + fk;
        bf16x8 k0 = *(const bf16x8*)kp;
        bf16x8 k1 = *(const bf16x8*)(kp + 32);
        f32x4 z; z[0] = 0.f; z[1] = 0.f; z[2] = 0.f; z[3] = 0.f;
        z = __builtin_amdgcn_mfma_f32_16x16x32_bf16(qfr0, k0, z, 0, 0, 0);
        z = __builtin_amdgcn_mfma_f32_16x16x32_bf16(qfr1, k1, z, 0, 0, 0);
        s[c] = z;
    }
    __syncthreads();   // all waves done reading Ks; safe to alias with Ps

    // ---- mask + softmax (registers only); write normalized P (bf16)
    float inv_row[4];
#pragma unroll
    for (int r = 0; r < 4; ++r) {
        int rl = 16 * wv + mbase + r;
        float mx = -INFINITY;
#pragma unroll
        for (int c = 0; c < 9; ++c) {
            int jt = 16 * (wv + c) + nloc;
            bool valid = (jt >= rl + 1) && (jt <= rl + 128) && (jbase + jt >= 0);
            float sv = valid ? s[c][r] : -INFINITY;
            s[c][r] = sv;
            mx = fmaxf(mx, sv);
        }
#pragma unroll
        for (int off = 8; off; off >>= 1) mx = fmaxf(mx, __shfl_xor(mx, off));
        float sum = 0.f;
#pragma unroll
        for (int c = 0; c < 9; ++c) {
            float p = __expf(s[c][r] - mx);
            s[c][r] = p;
            sum += p;
        }
#pragma unroll
        for (int off = 8; off; off >>= 1) sum += __shfl_xor(sum, off);
        inv_row[r] = 1.0f / sum;
    }

    __bf16* myP = KsPs + (size_t)wv * 16 * PPAD;
#pragma unroll
    for (int c = 0; c < 9; ++c)
#pragma unroll
        for (int r = 0; r < 4; ++r)
            myP[(mbase + r) * PPAD + 16 * c + nloc] = (__bf16)(s[c][r] * inv_row[r]);
#pragma unroll
    for (int r = 0; r < 4; ++r)       // zero P cols [144,160)
        myP[(mbase + r) * PPAD + 144 + nloc] = (__bf16)0.0f;

    asm volatile("" ::: "memory");
    __builtin_amdgcn_s_waitcnt(0);    // wave-local LDS write->read ordering

    // ---- O = P V  (5 k-steps of 32 keys, 4 d-tiles)
    f32x4 o[4];
#pragma unroll
    for (int j = 0; j < 4; ++j) { o[j][0] = 0.f; o[j][1] = 0.f; o[j][2] = 0.f; o[j][3] = 0.f; }
#pragma unroll
    for (int stp = 0; stp < 5; ++stp) {
        bf16x8 pf = *(const bf16x8*)(myP + nloc * PPAD + 32 * stp + fk);
#pragma unroll
        for (int j = 0; j < 4; ++j) {
            bf16x8 vf = *(const bf16x8*)(Vt + (size_t)(16 * j + nloc) * VPAD
                                         + 16 * wv + 32 * stp + fk);
            o[j] = __builtin_amdgcn_mfma_f32_16x16x32_bf16(pf, vf, o[j], 0, 0, 0);
        }
    }

    // ---- epilogue: C-layout -> global bf16
    __bf16* Og = Abf + (size_t)(b * SEQ + q0 + 16 * wv) * DMODEL + hoff;
#pragma unroll
    for (int j = 0; j < 4; ++j)
#pragma unroll
        for (int r = 0; r < 4; ++r)
            Og[(size_t)(mbase + r) * DMODEL + 16 * j + nloc] = (__bf16)o[j][r];
}

// ---------------------------------------------------------------------------
extern "C" void kernel_launch(void* const* d_in, const int* in_sizes, int n_in,
                              void* d_out, int out_size, void* d_ws, size_t ws_size,
                              hipStream_t stream)
{
    const float* X  = (const float*)d_in[0];
    const float* Wq = (const float*)d_in[1];
    const float* Wk = (const float*)d_in[2];
    const float* Wv = (const float*)d_in[3];
    const float* Wo = (const float*)d_in[4];
    const float* bo = (const float*)d_in[5];
    float* out = (float*)d_out;

    const size_t MB = 1ull << 20;
    __bf16* Xbf = (__bf16*)d_ws;                        // 8 MB; reused as Abf
    __bf16* Wbf = (__bf16*)((char*)d_ws + 8 * MB);      // 8 MB (Wq|Wk|Wv|Wo)
    __bf16* Qb  = (__bf16*)((char*)d_ws + 16 * MB);     // 8 MB
    __bf16* Kb  = (__bf16*)((char*)d_ws + 24 * MB);     // 8 MB
    __bf16* Vb  = (__bf16*)((char*)d_ws + 32 * MB);     // 8 MB
    float*  ctab = (float*)((char*)d_ws + 40 * MB);     // 256 KB
    float*  stab = (float*)((char*)d_ws + 41 * MB);     // 256 KB
    __bf16* Abf = Xbf;   // X dead after QKV projection

    // 1. fp32 -> bf16 conversion + RoPE table (fused)
    {
        int total = (ROWS * DMODEL + 4 * DMODEL * DMODEL) / 4 + SEQ * 32;
        convert_bf16<<<(total + 255) / 256, 256, 0, stream>>>(
            X, Wq, Wk, Wv, Wo, Xbf, Wbf, ctab, stab);
    }
    // 2. QKV projections with fused RoPE (+Q scale), bf16 out
    {
        dim3 grid(DMODEL / 128, ROWS / 128, 3);
        gemm_qkv_bf<<<grid, 256, 0, stream>>>(Xbf, Wbf, Qb, Kb, Vb, ctab, stab);
    }
    // 3. MFMA sliding-window attention -> bf16
    {
        dim3 grid(SEQ / QTILE, NHEADS, BATCH);
        attn_mfma<<<grid, 256, 0, stream>>>(Qb, Kb, Vb, Abf);
    }
    // 4. Output projection + bias (fp32 out)
    {
        dim3 grid(DMODEL / 128, ROWS / 128, 1);
        gemm_out_bf<<<grid, 256, 0, stream>>>(Abf, Wbf + 3ull * DMODEL * DMODEL, bo, out);
    }
}

// Round 5
// 169.037 us; speedup vs baseline: 8.4396x; 1.0924x over previous
//
#include <hip/hip_runtime.h>

// Problem constants (MultiAttention_61340722921598)
#define BATCH 2
#define SEQ   2048
#define DMODEL 1024
#define NHEADS 16
#define HDIM   64
#define WINDOW 128
#define ROWS  (BATCH * SEQ)          // 4096

typedef __bf16 bf16x8 __attribute__((ext_vector_type(8)));
typedef __bf16 bf16x4 __attribute__((ext_vector_type(4)));
typedef float  f32x4  __attribute__((ext_vector_type(4)));

// async global->LDS, 16B per lane; LDS dest = wave-uniform base + lane*16
__device__ __forceinline__ void async_load16(const __bf16* g, __bf16* l) {
    __builtin_amdgcn_global_load_lds(
        (const __attribute__((address_space(1))) unsigned int*)g,
        (__attribute__((address_space(3))) unsigned int*)l, 16, 0, 0);
}

// ---------------------------------------------------------------------------
// fp32 -> bf16 conversion of X and the 4 weights; tail range computes the
// RoPE cos/sin table (exact libm sincosf, matching the fp32 reference).
// ---------------------------------------------------------------------------
__global__ __launch_bounds__(256) void convert_bf16(
    const float* __restrict__ X,
    const float* __restrict__ Wq, const float* __restrict__ Wk,
    const float* __restrict__ Wv, const float* __restrict__ Wo,
    __bf16* __restrict__ Xbf, __bf16* __restrict__ Wbf,
    float* __restrict__ ct, float* __restrict__ st)
{
    const int XN = ROWS * DMODEL / 4;     // 1,048,576 groups
    const int WN = DMODEL * DMODEL / 4;   // 262,144 per W
    const int TOT = XN + 4 * WN;          // 2,097,152
    int idx = blockIdx.x * blockDim.x + threadIdx.x;

    if (idx < TOT) {
        const float* src;
        __bf16* dst;
        if (idx < XN) {
            src = X + (size_t)idx * 4;
            dst = Xbf + (size_t)idx * 4;
        } else {
            int rel = idx - XN;
            int w = rel / WN;
            int off = rel - w * WN;
            const float* Wp = (w == 0) ? Wq : (w == 1) ? Wk : (w == 2) ? Wv : Wo;
            src = Wp + (size_t)off * 4;
            dst = Wbf + (size_t)rel * 4;
        }
        float4 v = *(const float4*)src;
        bf16x4 o;
        o[0] = (__bf16)v.x; o[1] = (__bf16)v.y; o[2] = (__bf16)v.z; o[3] = (__bf16)v.w;
        *(bf16x4*)dst = o;
    } else if (idx < TOT + SEQ * 32) {
        int k = idx - TOT;
        int t = k >> 5, d = k & 31;
        float ang = (float)t * expf(-(float)d * 0.28782313662425572f); // ln(1e4)/32
        float s, c;
        sincosf(ang, &s, &c);
        ct[k] = c; st[k] = s;
    }
}

// ---------------------------------------------------------------------------
// bf16 MFMA GEMM: C[m][n] = sum_k A[m][k] * B[n][k], m97-style staging.
// Tile TM x 128, BK=64 (two 32-wide halves, each staged/swizzled exactly as
// the round-4 verified pattern: LDS row r slot s holds global chunk
// s^((r>>1)&3); staged via source-address permutation so global segments are
// unchanged). 256 threads = 4 waves (2x2); wave covers (TM/2) x 64 via
// (TM/32) x 4 tiles of 16x16x32 MFMA, two k-halves per iteration.
//   TM=128: QKV projections, grid 768 (3 blocks/CU), 16 barrier-pairs.
//   TM=64 : output projection, grid 512 (2 blocks/CU).
// Epilogue modes: 0=Q (RoPE+0.125, bf16), 1=K (RoPE, bf16), 2=V (bf16),
// 3=fp32+bias.
// A/B-frag: elem[row=lane&15][k=(lane>>4)*8+j]; C/D: col=lane&15,
// row=(lane>>4)*4+reg (verified m89, rounds 2-4).
// ---------------------------------------------------------------------------
template<int TM>
__device__ __forceinline__ void gemm_mfma_body(
    const __bf16* __restrict__ A, const __bf16* __restrict__ B,
    void* __restrict__ Cout, const float* __restrict__ bias,
    const float* __restrict__ ct, const float* __restrict__ st,
    int mode, int N, int K, int m0, int n0)
{
    constexpr int NI = TM / 32;            // i-tiles per wave (4 or 2)
    __shared__ __bf16 As[2][TM * 32];      // two k-halves
    __shared__ __bf16 Bs[2][128 * 32];

    const int tid  = threadIdx.x;
    const int lane = tid & 63;
    const int wv   = tid >> 6;
    const int wrow = (wv >> 1) * (TM / 2);
    const int wcol = (wv & 1) * 64;

    // staging map (per 32-wide half, round-4 verified): one call = 16 rows,
    // lane -> row lane>>2, slot lane&3, source chunk (lane&3)^((lane>>3)&3)
    const int srow = lane >> 2;
    const int schk = (lane & 3) ^ ((lane >> 3) & 3);
    const int arbase = (TM == 128) ? 32 * wv : 16 * wv;
    const int brbase = 32 * wv;

    const __bf16* gA0 = A + (size_t)(m0 + arbase + srow) * K + 8 * schk;
    const __bf16* gA1 = gA0 + (size_t)16 * K;                 // TM=128 only
    const __bf16* gB0 = B + (size_t)(n0 + brbase + srow) * K + 8 * schk;
    const __bf16* gB1 = gB0 + (size_t)16 * K;

    // fragment read map: row frow, global chunk lane>>4 at swizzled slot
    const int frow = lane & 15;
    const int fsw  = 8 * ((lane >> 4) ^ ((frow >> 1) & 3));

    f32x4 acc[NI][4];
#pragma unroll
    for (int i = 0; i < NI; ++i)
#pragma unroll
        for (int j = 0; j < 4; ++j) {
            acc[i][j][0] = 0.f; acc[i][j][1] = 0.f;
            acc[i][j][2] = 0.f; acc[i][j][3] = 0.f;
        }

    for (int k0 = 0; k0 < K; k0 += 64) {
        __syncthreads();                 // prior iter's LDS reads complete
#pragma unroll
        for (int h = 0; h < 2; ++h) {
            async_load16(gA0 + k0 + 32 * h, As[h] + arbase * 32);
            if (TM == 128)
                async_load16(gA1 + k0 + 32 * h, As[h] + (arbase + 16) * 32);
            async_load16(gB0 + k0 + 32 * h, Bs[h] + brbase * 32);
            async_load16(gB1 + k0 + 32 * h, Bs[h] + (brbase + 16) * 32);
        }
        __syncthreads();                 // drains vmcnt: staging visible

#pragma unroll
        for (int h = 0; h < 2; ++h) {
            bf16x8 afr[NI], bfr[4];
#pragma unroll
            for (int i = 0; i < NI; ++i)
                afr[i] = *(const bf16x8*)(As[h] + (wrow + 16 * i + frow) * 32 + fsw);
#pragma unroll
            for (int j = 0; j < 4; ++j)
                bfr[j] = *(const bf16x8*)(Bs[h] + (wcol + 16 * j + frow) * 32 + fsw);
#pragma unroll
            for (int i = 0; i < NI; ++i)
#pragma unroll
                for (int j = 0; j < 4; ++j)
                    acc[i][j] = __builtin_amdgcn_mfma_f32_16x16x32_bf16(
                        afr[i], bfr[j], acc[i][j], 0, 0, 0);
        }
    }

#pragma unroll
    for (int i = 0; i < NI; ++i) {
#pragma unroll
        for (int r = 0; r < 4; ++r) {
            int row = m0 + wrow + i * 16 + (lane >> 4) * 4 + r;
            if (mode <= 1) {
                // RoPE: pairs (d, d+32) in (acc[i][j], acc[i][j+2]), d=j*16+(lane&15)<32
                int t = row & (SEQ - 1);
#pragma unroll
                for (int j = 0; j < 2; ++j) {
                    int dd = j * 16 + (lane & 15);
                    float c = ct[t * 32 + dd];
                    float s = st[t * 32 + dd];
                    float v0 = acc[i][j][r], v1 = acc[i][j + 2][r];
                    float n0v = v0 * c - v1 * s;
                    float n1v = v1 * c + v0 * s;
                    if (mode == 0) { n0v *= 0.125f; n1v *= 0.125f; }
                    acc[i][j][r] = n0v; acc[i][j + 2][r] = n1v;
                }
            }
#pragma unroll
            for (int j = 0; j < 4; ++j) {
                int col = n0 + wcol + j * 16 + (lane & 15);
                float v = acc[i][j][r];
                if (mode == 3)
                    ((float*)Cout)[(size_t)row * N + col] = v + bias[col];
                else
                    ((__bf16*)Cout)[(size_t)row * N + col] = (__bf16)v;
            }
        }
    }
}

__global__ __launch_bounds__(256) void gemm_qkv_bf(
    const __bf16* __restrict__ X, const __bf16* __restrict__ Wbf,
    __bf16* __restrict__ Qb, __bf16* __restrict__ Kb, __bf16* __restrict__ Vb,
    const float* __restrict__ ct, const float* __restrict__ st)
{
    const int z = blockIdx.z;
    const __bf16* W = Wbf + (size_t)z * (DMODEL * DMODEL);
    __bf16* C = (z == 0) ? Qb : (z == 1) ? Kb : Vb;
    gemm_mfma_body<128>(X, W, C, nullptr, ct, st, z, DMODEL, DMODEL,
                        blockIdx.y * 128, blockIdx.x * 128);
}

__global__ __launch_bounds__(256) void gemm_out_bf(
    const __bf16* __restrict__ Abf, const __bf16* __restrict__ Wo,
    const float* __restrict__ bias, float* __restrict__ out)
{
    gemm_mfma_body<64>(Abf, Wo, out, bias, nullptr, nullptr, 3, DMODEL, DMODEL,
                       blockIdx.y * 64, blockIdx.x * 128);
}

// ---------------------------------------------------------------------------
// MFMA sliding-window attention (verified rounds 3-4). One 256-thread block
// per (b, h, 64 q-rows); wave w owns q-rows 16w..16w+15.
// ---------------------------------------------------------------------------
#define QTILE 64
#define KPAD  72    // Ks row (bf16): 36 words/row -> 8 distinct bank offsets
#define VPAD  216   // Vt row: 108 words -> 8 distinct offsets
#define PPAD  168   // Ps row: 84 words -> 8 distinct offsets

__global__ __launch_bounds__(256) void attn_mfma(
    const __bf16* __restrict__ Qb, const __bf16* __restrict__ Kb,
    const __bf16* __restrict__ Vb, __bf16* __restrict__ Abf)
{
    __shared__ __bf16 KsPs[192 * KPAD];  // 27648 B; Ks, then reused as Ps
    __shared__ __bf16 Vt[64 * VPAD];     // 27648 B  (total 55296 B)

    const int tid  = threadIdx.x;
    const int lane = tid & 63;
    const int wv   = tid >> 6;
    const int q0   = blockIdx.x * QTILE;
    const int h    = blockIdx.y;
    const int b    = blockIdx.z;
    const int jbase = q0 - 128;
    const size_t hoff = (size_t)h * HDIM;
    const int nloc  = lane & 15;
    const int mbase = (lane >> 4) * 4;
    const int fk    = (lane >> 4) * 8;

    const __bf16* Kg = Kb + (size_t)(b * SEQ) * DMODEL + hoff;
    const __bf16* Vg = Vb + (size_t)(b * SEQ) * DMODEL + hoff;

    // ---- stage Ks (natural) + Vt (transposed)
#pragma unroll
    for (int it = 0; it < 6; ++it) {
        int idx = tid + it * 256;          // 0..1535
        int jt = idx >> 3;                 // 0..191
        int dq = (idx & 7) * 8;
        int jg = jbase + jt;
        int jc = jg < 0 ? 0 : jg;          // clamp; masked via p=0 later
        bf16x8 kv = *(const bf16x8*)(Kg + (size_t)jc * DMODEL + dq);
        bf16x8 vv = *(const bf16x8*)(Vg + (size_t)jc * DMODEL + dq);
        *(bf16x8*)(KsPs + jt * KPAD + dq) = kv;
#pragma unroll
        for (int e = 0; e < 8; ++e) Vt[(dq + e) * VPAD + jt] = vv[e];
    }
    // zero Vt cols [192,208) (read by PV k-steps; must not be garbage)
#pragma unroll
    for (int it = 0; it < 4; ++it) {
        int idx = tid + it * 256;          // 0..1023
        int d = idx >> 4, c = idx & 15;
        Vt[d * VPAD + 192 + c] = (__bf16)0.0f;
    }
    __syncthreads();

    // ---- Q A-frags direct from global
    const __bf16* Qg = Qb + (size_t)(b * SEQ + q0 + 16 * wv + nloc) * DMODEL + hoff + fk;
    bf16x8 qfr0 = *(const bf16x8*)(Qg);
    bf16x8 qfr1 = *(const bf16x8*)(Qg + 32);

    // ---- S = Q K^T over 9 column tiles
    f32x4 s[9];
#pragma unroll
    for (int c = 0; c < 9; ++c) {
        const __bf16* kp = KsPs + (size_t)(16 * (wv + c) + nloc) * KPAD + fk;
        bf16x8 k0 = *(const bf16x8*)kp;
        bf16x8 k1 = *(const bf16x8*)(kp + 32);
        f32x4 z; z[0] = 0.f; z[1] = 0.f; z[2] = 0.f; z[3] = 0.f;
        z = __builtin_amdgcn_mfma_f32_16x16x32_bf16(qfr0, k0, z, 0, 0, 0);
        z = __builtin_amdgcn_mfma_f32_16x16x32_bf16(qfr1, k1, z, 0, 0, 0);
        s[c] = z;
    }
    __syncthreads();   // all waves done reading Ks; safe to alias with Ps

    // ---- mask + softmax (registers only); write normalized P (bf16)
    float inv_row[4];
#pragma unroll
    for (int r = 0; r < 4; ++r) {
        int rl = 16 * wv + mbase + r;
        float mx = -INFINITY;
#pragma unroll
        for (int c = 0; c < 9; ++c) {
            int jt = 16 * (wv + c) + nloc;
            bool valid = (jt >= rl + 1) && (jt <= rl + 128) && (jbase + jt >= 0);
            float sv = valid ? s[c][r] : -INFINITY;
            s[c][r] = sv;
            mx = fmaxf(mx, sv);
        }
#pragma unroll
        for (int off = 8; off; off >>= 1) mx = fmaxf(mx, __shfl_xor(mx, off));
        float sum = 0.f;
#pragma unroll
        for (int c = 0; c < 9; ++c) {
            float p = __expf(s[c][r] - mx);
            s[c][r] = p;
            sum += p;
        }
#pragma unroll
        for (int off = 8; off; off >>= 1) sum += __shfl_xor(sum, off);
        inv_row[r] = 1.0f / sum;
    }

    __bf16* myP = KsPs + (size_t)wv * 16 * PPAD;
#pragma unroll
    for (int c = 0; c < 9; ++c)
#pragma unroll
        for (int r = 0; r < 4; ++r)
            myP[(mbase + r) * PPAD + 16 * c + nloc] = (__bf16)(s[c][r] * inv_row[r]);
#pragma unroll
    for (int r = 0; r < 4; ++r)       // zero P cols [144,160)
        myP[(mbase + r) * PPAD + 144 + nloc] = (__bf16)0.0f;

    asm volatile("" ::: "memory");
    __builtin_amdgcn_s_waitcnt(0);    // wave-local LDS write->read ordering

    // ---- O = P V  (5 k-steps of 32 keys, 4 d-tiles)
    f32x4 o[4];
#pragma unroll
    for (int j = 0; j < 4; ++j) { o[j][0] = 0.f; o[j][1] = 0.f; o[j][2] = 0.f; o[j][3] = 0.f; }
#pragma unroll
    for (int stp = 0; stp < 5; ++stp) {
        bf16x8 pf = *(const bf16x8*)(myP + nloc * PPAD + 32 * stp + fk);
#pragma unroll
        for (int j = 0; j < 4; ++j) {
            bf16x8 vf = *(const bf16x8*)(Vt + (size_t)(16 * j + nloc) * VPAD
                                         + 16 * wv + 32 * stp + fk);
            o[j] = __builtin_amdgcn_mfma_f32_16x16x32_bf16(pf, vf, o[j], 0, 0, 0);
        }
    }

    // ---- epilogue: C-layout -> global bf16
    __bf16* Og = Abf + (size_t)(b * SEQ + q0 + 16 * wv) * DMODEL + hoff;
#pragma unroll
    for (int j = 0; j < 4; ++j)
#pragma unroll
        for (int r = 0; r < 4; ++r)
            Og[(size_t)(mbase + r) * DMODEL + 16 * j + nloc] = (__bf16)o[j][r];
}

// ---------------------------------------------------------------------------
extern "C" void kernel_launch(void* const* d_in, const int* in_sizes, int n_in,
                              void* d_out, int out_size, void* d_ws, size_t ws_size,
                              hipStream_t stream)
{
    const float* X  = (const float*)d_in[0];
    const float* Wq = (const float*)d_in[1];
    const float* Wk = (const float*)d_in[2];
    const float* Wv = (const float*)d_in[3];
    const float* Wo = (const float*)d_in[4];
    const float* bo = (const float*)d_in[5];
    float* out = (float*)d_out;

    const size_t MB = 1ull << 20;
    __bf16* Xbf = (__bf16*)d_ws;                        // 8 MB; reused as Abf
    __bf16* Wbf = (__bf16*)((char*)d_ws + 8 * MB);      // 8 MB (Wq|Wk|Wv|Wo)
    __bf16* Qb  = (__bf16*)((char*)d_ws + 16 * MB);     // 8 MB
    __bf16* Kb  = (__bf16*)((char*)d_ws + 24 * MB);     // 8 MB
    __bf16* Vb  = (__bf16*)((char*)d_ws + 32 * MB);     // 8 MB
    float*  ctab = (float*)((char*)d_ws + 40 * MB);     // 256 KB
    float*  stab = (float*)((char*)d_ws + 41 * MB);     // 256 KB
    __bf16* Abf = Xbf;   // X dead after QKV projection

    // 1. fp32 -> bf16 conversion + RoPE table (fused)
    {
        int total = (ROWS * DMODEL + 4 * DMODEL * DMODEL) / 4 + SEQ * 32;
        convert_bf16<<<(total + 255) / 256, 256, 0, stream>>>(
            X, Wq, Wk, Wv, Wo, Xbf, Wbf, ctab, stab);
    }
    // 2. QKV projections with fused RoPE (+Q scale), bf16 out
    {
        dim3 grid(DMODEL / 128, ROWS / 128, 3);
        gemm_qkv_bf<<<grid, 256, 0, stream>>>(Xbf, Wbf, Qb, Kb, Vb, ctab, stab);
    }
    // 3. MFMA sliding-window attention -> bf16
    {
        dim3 grid(SEQ / QTILE, NHEADS, BATCH);
        attn_mfma<<<grid, 256, 0, stream>>>(Qb, Kb, Vb, Abf);
    }
    // 4. Output projection + bias (fp32 out), 64x128 tiles for 2 blocks/CU
    {
        dim3 grid(DMODEL / 128, ROWS / 64, 1);
        gemm_out_bf<<<grid, 256, 0, stream>>>(Abf, Wbf + 3ull * DMODEL * DMODEL, bo, out);
    }
}

// Round 6
// 166.181 us; speedup vs baseline: 8.5846x; 1.0172x over previous
//
#include <hip/hip_runtime.h>

// Problem constants (MultiAttention_61340722921598)
#define BATCH 2
#define SEQ   2048
#define DMODEL 1024
#define NHEADS 16
#define HDIM   64
#define WINDOW 128
#define ROWS  (BATCH * SEQ)          // 4096

typedef __bf16 bf16x8 __attribute__((ext_vector_type(8)));
typedef __bf16 bf16x4 __attribute__((ext_vector_type(4)));
typedef float  f32x4  __attribute__((ext_vector_type(4)));

// async global->LDS, 16B per lane; LDS dest = wave-uniform base + lane*16
__device__ __forceinline__ void async_load16(const __bf16* g, __bf16* l) {
    __builtin_amdgcn_global_load_lds(
        (const __attribute__((address_space(1))) unsigned int*)g,
        (__attribute__((address_space(3))) unsigned int*)l, 16, 0, 0);
}

// ---------------------------------------------------------------------------
// fp32 -> bf16 conversion of X and the 4 weights; tail range computes the
// RoPE cos/sin table (exact libm sincosf, matching the fp32 reference).
// ---------------------------------------------------------------------------
__global__ __launch_bounds__(256) void convert_bf16(
    const float* __restrict__ X,
    const float* __restrict__ Wq, const float* __restrict__ Wk,
    const float* __restrict__ Wv, const float* __restrict__ Wo,
    __bf16* __restrict__ Xbf, __bf16* __restrict__ Wbf,
    float* __restrict__ ct, float* __restrict__ st)
{
    const int XN = ROWS * DMODEL / 4;     // 1,048,576 groups
    const int WN = DMODEL * DMODEL / 4;   // 262,144 per W
    const int TOT = XN + 4 * WN;          // 2,097,152
    int idx = blockIdx.x * blockDim.x + threadIdx.x;

    if (idx < TOT) {
        const float* src;
        __bf16* dst;
        if (idx < XN) {
            src = X + (size_t)idx * 4;
            dst = Xbf + (size_t)idx * 4;
        } else {
            int rel = idx - XN;
            int w = rel / WN;
            int off = rel - w * WN;
            const float* Wp = (w == 0) ? Wq : (w == 1) ? Wk : (w == 2) ? Wv : Wo;
            src = Wp + (size_t)off * 4;
            dst = Wbf + (size_t)rel * 4;
        }
        float4 v = *(const float4*)src;
        bf16x4 o;
        o[0] = (__bf16)v.x; o[1] = (__bf16)v.y; o[2] = (__bf16)v.z; o[3] = (__bf16)v.w;
        *(bf16x4*)dst = o;
    } else if (idx < TOT + SEQ * 32) {
        int k = idx - TOT;
        int t = k >> 5, d = k & 31;
        float ang = (float)t * expf(-(float)d * 0.28782313662425572f); // ln(1e4)/32
        float s, c;
        sincosf(ang, &s, &c);
        ct[k] = c; st[k] = s;
    }
}

// ---------------------------------------------------------------------------
// bf16 MFMA GEMM: C[m][n] = sum_k A[m][k] * B[n][k], m97-style staging.
// Tile TM x TN, BK=64 (two 32-wide halves, each staged/swizzled per the
// round-4 verified pattern: LDS row r slot s holds global chunk s^((r>>1)&3),
// applied via source-address permutation -> coalescing unchanged, 0
// conflicts measured). 256 threads = 4 waves in a 4x1 layout: wave wv covers
// rows [wv*TM/4, +TM/4) x all TN cols -> NI = TM/64 i-tiles, NJ = TN/16
// j-tiles of 16x16x32 MFMA, two k-halves per iteration.
// 4x1 layout keeps RoPE pairs (d, d+32) within one wave (acc j, j+2) for
// TN=64 (one head per n-tile; n0 % 64 == 0).
//   qkv: TM=128, TN=64, grid (16,32,3) = 1536 blocks = 6/CU (LDS 24.6 KB).
//   out: TM=64,  TN=64, grid (16,64)   = 1024 blocks = 4/CU.
// Epilogue modes: 0=Q (RoPE+0.125, bf16), 1=K (RoPE, bf16), 2=V (bf16),
// 3=fp32+bias.
// A/B-frag: elem[row=lane&15][k=(lane>>4)*8+j]; C/D: col=lane&15,
// row=(lane>>4)*4+reg (verified m89, rounds 2-5).
// ---------------------------------------------------------------------------
template<int TM, int TN>
__device__ __forceinline__ void gemm_mfma_body(
    const __bf16* __restrict__ A, const __bf16* __restrict__ B,
    void* __restrict__ Cout, const float* __restrict__ bias,
    const float* __restrict__ ct, const float* __restrict__ st,
    int mode, int N, int K, int m0, int n0)
{
    constexpr int NI = TM / 64;            // i-tiles per wave (2 or 1)
    constexpr int NJ = TN / 16;            // j-tiles per wave (4)
    constexpr int NA = TM / 64;            // A staging calls per wave per half
    constexpr int NB = TN / 64;            // B staging calls per wave per half
    __shared__ __bf16 As[2][TM * 32];      // two k-halves
    __shared__ __bf16 Bs[2][TN * 32];

    const int tid  = threadIdx.x;
    const int lane = tid & 63;
    const int wv   = tid >> 6;
    const int wrow = wv * (TM / 4);        // wave's row range (== its staging range)

    // staging map (per 32-wide half): one call = 16 rows,
    // lane -> row lane>>2, slot lane&3, source chunk (lane&3)^((lane>>3)&3)
    const int srow = lane >> 2;
    const int schk = (lane & 3) ^ ((lane >> 3) & 3);
    const int arbase = wv * (TM / 4);
    const int brbase = wv * (TN / 4);

    const __bf16* gA0 = A + (size_t)(m0 + arbase + srow) * K + 8 * schk;
    const __bf16* gA1 = gA0 + (size_t)16 * K;                 // NA==2 only
    const __bf16* gB0 = B + (size_t)(n0 + brbase + srow) * K + 8 * schk;

    // fragment read map: row frow, global chunk lane>>4 at swizzled slot
    const int frow = lane & 15;
    const int fsw  = 8 * ((lane >> 4) ^ ((frow >> 1) & 3));

    f32x4 acc[NI][NJ];
#pragma unroll
    for (int i = 0; i < NI; ++i)
#pragma unroll
        for (int j = 0; j < NJ; ++j) {
            acc[i][j][0] = 0.f; acc[i][j][1] = 0.f;
            acc[i][j][2] = 0.f; acc[i][j][3] = 0.f;
        }

    for (int k0 = 0; k0 < K; k0 += 64) {
        __syncthreads();                 // prior iter's LDS reads complete
#pragma unroll
        for (int h = 0; h < 2; ++h) {
            async_load16(gA0 + k0 + 32 * h, As[h] + arbase * 32);
            if (NA == 2)
                async_load16(gA1 + k0 + 32 * h, As[h] + (arbase + 16) * 32);
            async_load16(gB0 + k0 + 32 * h, Bs[h] + brbase * 32);
        }
        __syncthreads();                 // drains vmcnt: staging visible

#pragma unroll
        for (int h = 0; h < 2; ++h) {
            bf16x8 afr[NI], bfr[NJ];
#pragma unroll
            for (int i = 0; i < NI; ++i)
                afr[i] = *(const bf16x8*)(As[h] + (wrow + 16 * i + frow) * 32 + fsw);
#pragma unroll
            for (int j = 0; j < NJ; ++j)
                bfr[j] = *(const bf16x8*)(Bs[h] + (16 * j + frow) * 32 + fsw);
#pragma unroll
            for (int i = 0; i < NI; ++i)
#pragma unroll
                for (int j = 0; j < NJ; ++j)
                    acc[i][j] = __builtin_amdgcn_mfma_f32_16x16x32_bf16(
                        afr[i], bfr[j], acc[i][j], 0, 0, 0);
        }
    }

#pragma unroll
    for (int i = 0; i < NI; ++i) {
#pragma unroll
        for (int r = 0; r < 4; ++r) {
            int row = m0 + wrow + i * 16 + (lane >> 4) * 4 + r;
            if (mode <= 1) {
                // RoPE: pairs (d, d+32) in (acc[i][j], acc[i][j+2]), d=j*16+(lane&15)<32
                int t = row & (SEQ - 1);
#pragma unroll
                for (int j = 0; j < 2; ++j) {
                    int dd = j * 16 + (lane & 15);
                    float c = ct[t * 32 + dd];
                    float s = st[t * 32 + dd];
                    float v0 = acc[i][j][r], v1 = acc[i][j + 2][r];
                    float n0v = v0 * c - v1 * s;
                    float n1v = v1 * c + v0 * s;
                    if (mode == 0) { n0v *= 0.125f; n1v *= 0.125f; }
                    acc[i][j][r] = n0v; acc[i][j + 2][r] = n1v;
                }
            }
#pragma unroll
            for (int j = 0; j < NJ; ++j) {
                int col = n0 + j * 16 + (lane & 15);
                float v = acc[i][j][r];
                if (mode == 3)
                    ((float*)Cout)[(size_t)row * N + col] = v + bias[col];
                else
                    ((__bf16*)Cout)[(size_t)row * N + col] = (__bf16)v;
            }
        }
    }
}

__global__ __launch_bounds__(256) void gemm_qkv_bf(
    const __bf16* __restrict__ X, const __bf16* __restrict__ Wbf,
    __bf16* __restrict__ Qb, __bf16* __restrict__ Kb, __bf16* __restrict__ Vb,
    const float* __restrict__ ct, const float* __restrict__ st)
{
    const int z = blockIdx.z;
    const __bf16* W = Wbf + (size_t)z * (DMODEL * DMODEL);
    __bf16* C = (z == 0) ? Qb : (z == 1) ? Kb : Vb;
    gemm_mfma_body<128, 64>(X, W, C, nullptr, ct, st, z, DMODEL, DMODEL,
                            blockIdx.y * 128, blockIdx.x * 64);
}

__global__ __launch_bounds__(256) void gemm_out_bf(
    const __bf16* __restrict__ Abf, const __bf16* __restrict__ Wo,
    const float* __restrict__ bias, float* __restrict__ out)
{
    gemm_mfma_body<64, 64>(Abf, Wo, out, bias, nullptr, nullptr, 3,
                           DMODEL, DMODEL, blockIdx.y * 64, blockIdx.x * 64);
}

// ---------------------------------------------------------------------------
// MFMA sliding-window attention (verified rounds 3-5). One 256-thread block
// per (b, h, 64 q-rows); wave w owns q-rows 16w..16w+15.
// ---------------------------------------------------------------------------
#define QTILE 64
#define KPAD  72    // Ks row (bf16): 36 words/row -> 8 distinct bank offsets
#define VPAD  216   // Vt row: 108 words -> 8 distinct offsets
#define PPAD  168   // Ps row: 84 words -> 8 distinct offsets

__global__ __launch_bounds__(256) void attn_mfma(
    const __bf16* __restrict__ Qb, const __bf16* __restrict__ Kb,
    const __bf16* __restrict__ Vb, __bf16* __restrict__ Abf)
{
    __shared__ __bf16 KsPs[192 * KPAD];  // 27648 B; Ks, then reused as Ps
    __shared__ __bf16 Vt[64 * VPAD];     // 27648 B  (total 55296 B)

    const int tid  = threadIdx.x;
    const int lane = tid & 63;
    const int wv   = tid >> 6;
    const int q0   = blockIdx.x * QTILE;
    const int h    = blockIdx.y;
    const int b    = blockIdx.z;
    const int jbase = q0 - 128;
    const size_t hoff = (size_t)h * HDIM;
    const int nloc  = lane & 15;
    const int mbase = (lane >> 4) * 4;
    const int fk    = (lane >> 4) * 8;

    const __bf16* Kg = Kb + (size_t)(b * SEQ) * DMODEL + hoff;
    const __bf16* Vg = Vb + (size_t)(b * SEQ) * DMODEL + hoff;

    // ---- stage Ks (natural) + Vt (transposed)
#pragma unroll
    for (int it = 0; it < 6; ++it) {
        int idx = tid + it * 256;          // 0..1535
        int jt = idx >> 3;                 // 0..191
        int dq = (idx & 7) * 8;
        int jg = jbase + jt;
        int jc = jg < 0 ? 0 : jg;          // clamp; masked via p=0 later
        bf16x8 kv = *(const bf16x8*)(Kg + (size_t)jc * DMODEL + dq);
        bf16x8 vv = *(const bf16x8*)(Vg + (size_t)jc * DMODEL + dq);
        *(bf16x8*)(KsPs + jt * KPAD + dq) = kv;
#pragma unroll
        for (int e = 0; e < 8; ++e) Vt[(dq + e) * VPAD + jt] = vv[e];
    }
    // zero Vt cols [192,208) (read by PV k-steps; must not be garbage)
#pragma unroll
    for (int it = 0; it < 4; ++it) {
        int idx = tid + it * 256;          // 0..1023
        int d = idx >> 4, c = idx & 15;
        Vt[d * VPAD + 192 + c] = (__bf16)0.0f;
    }
    __syncthreads();

    // ---- Q A-frags direct from global
    const __bf16* Qg = Qb + (size_t)(b * SEQ + q0 + 16 * wv + nloc) * DMODEL + hoff + fk;
    bf16x8 qfr0 = *(const bf16x8*)(Qg);
    bf16x8 qfr1 = *(const bf16x8*)(Qg + 32);

    // ---- S = Q K^T over 9 column tiles
    f32x4 s[9];
#pragma unroll
    for (int c = 0; c < 9; ++c) {
        const __bf16* kp = KsPs + (size_t)(16 * (wv + c) + nloc) * KPAD + fk;
        bf16x8 k0 = *(const bf16x8*)kp;
        bf16x8 k1 = *(const bf16x8*)(kp + 32);
        f32x4 z; z[0] = 0.f; z[1] = 0.f; z[2] = 0.f; z[3] = 0.f;
        z = __builtin_amdgcn_mfma_f32_16x16x32_bf16(qfr0, k0, z, 0, 0, 0);
        z = __builtin_amdgcn_mfma_f32_16x16x32_bf16(qfr1, k1, z, 0, 0, 0);
        s[c] = z;
    }
    __syncthreads();   // all waves done reading Ks; safe to alias with Ps

    // ---- mask + softmax (registers only); write normalized P (bf16)
    float inv_row[4];
#pragma unroll
    for (int r = 0; r < 4; ++r) {
        int rl = 16 * wv + mbase + r;
        float mx = -INFINITY;
#pragma unroll
        for (int c = 0; c < 9; ++c) {
            int jt = 16 * (wv + c) + nloc;
            bool valid = (jt >= rl + 1) && (jt <= rl + 128) && (jbase + jt >= 0);
            float sv = valid ? s[c][r] : -INFINITY;
            s[c][r] = sv;
            mx = fmaxf(mx, sv);
        }
#pragma unroll
        for (int off = 8; off; off >>= 1) mx = fmaxf(mx, __shfl_xor(mx, off));
        float sum = 0.f;
#pragma unroll
        for (int c = 0; c < 9; ++c) {
            float p = __expf(s[c][r] - mx);
            s[c][r] = p;
            sum += p;
        }
#pragma unroll
        for (int off = 8; off; off >>= 1) sum += __shfl_xor(sum, off);
        inv_row[r] = 1.0f / sum;
    }

    __bf16* myP = KsPs + (size_t)wv * 16 * PPAD;
#pragma unroll
    for (int c = 0; c < 9; ++c)
#pragma unroll
        for (int r = 0; r < 4; ++r)
            myP[(mbase + r) * PPAD + 16 * c + nloc] = (__bf16)(s[c][r] * inv_row[r]);
#pragma unroll
    for (int r = 0; r < 4; ++r)       // zero P cols [144,160)
        myP[(mbase + r) * PPAD + 144 + nloc] = (__bf16)0.0f;

    asm volatile("" ::: "memory");
    __builtin_amdgcn_s_waitcnt(0);    // wave-local LDS write->read ordering

    // ---- O = P V  (5 k-steps of 32 keys, 4 d-tiles)
    f32x4 o[4];
#pragma unroll
    for (int j = 0; j < 4; ++j) { o[j][0] = 0.f; o[j][1] = 0.f; o[j][2] = 0.f; o[j][3] = 0.f; }
#pragma unroll
    for (int stp = 0; stp < 5; ++stp) {
        bf16x8 pf = *(const bf16x8*)(myP + nloc * PPAD + 32 * stp + fk);
#pragma unroll
        for (int j = 0; j < 4; ++j) {
            bf16x8 vf = *(const bf16x8*)(Vt + (size_t)(16 * j + nloc) * VPAD
                                         + 16 * wv + 32 * stp + fk);
            o[j] = __builtin_amdgcn_mfma_f32_16x16x32_bf16(pf, vf, o[j], 0, 0, 0);
        }
    }

    // ---- epilogue: C-layout -> global bf16
    __bf16* Og = Abf + (size_t)(b * SEQ + q0 + 16 * wv) * DMODEL + hoff;
#pragma unroll
    for (int j = 0; j < 4; ++j)
#pragma unroll
        for (int r = 0; r < 4; ++r)
            Og[(size_t)(mbase + r) * DMODEL + 16 * j + nloc] = (__bf16)o[j][r];
}

// ---------------------------------------------------------------------------
extern "C" void kernel_launch(void* const* d_in, const int* in_sizes, int n_in,
                              void* d_out, int out_size, void* d_ws, size_t ws_size,
                              hipStream_t stream)
{
    const float* X  = (const float*)d_in[0];
    const float* Wq = (const float*)d_in[1];
    const float* Wk = (const float*)d_in[2];
    const float* Wv = (const float*)d_in[3];
    const float* Wo = (const float*)d_in[4];
    const float* bo = (const float*)d_in[5];
    float* out = (float*)d_out;

    const size_t MB = 1ull << 20;
    __bf16* Xbf = (__bf16*)d_ws;                        // 8 MB; reused as Abf
    __bf16* Wbf = (__bf16*)((char*)d_ws + 8 * MB);      // 8 MB (Wq|Wk|Wv|Wo)
    __bf16* Qb  = (__bf16*)((char*)d_ws + 16 * MB);     // 8 MB
    __bf16* Kb  = (__bf16*)((char*)d_ws + 24 * MB);     // 8 MB
    __bf16* Vb  = (__bf16*)((char*)d_ws + 32 * MB);     // 8 MB
    float*  ctab = (float*)((char*)d_ws + 40 * MB);     // 256 KB
    float*  stab = (float*)((char*)d_ws + 41 * MB);     // 256 KB
    __bf16* Abf = Xbf;   // X dead after QKV projection

    // 1. fp32 -> bf16 conversion + RoPE table (fused)
    {
        int total = (ROWS * DMODEL + 4 * DMODEL * DMODEL) / 4 + SEQ * 32;
        convert_bf16<<<(total + 255) / 256, 256, 0, stream>>>(
            X, Wq, Wk, Wv, Wo, Xbf, Wbf, ctab, stab);
    }
    // 2. QKV projections with fused RoPE (+Q scale), bf16 out; 128x64 tiles
    {
        dim3 grid(DMODEL / 64, ROWS / 128, 3);
        gemm_qkv_bf<<<grid, 256, 0, stream>>>(Xbf, Wbf, Qb, Kb, Vb, ctab, stab);
    }
    // 3. MFMA sliding-window attention -> bf16
    {
        dim3 grid(SEQ / QTILE, NHEADS, BATCH);
        attn_mfma<<<grid, 256, 0, stream>>>(Qb, Kb, Vb, Abf);
    }
    // 4. Output projection + bias (fp32 out); 64x64 tiles
    {
        dim3 grid(DMODEL / 64, ROWS / 64, 1);
        gemm_out_bf<<<grid, 256, 0, stream>>>(Abf, Wbf + 3ull * DMODEL * DMODEL, bo, out);
    }
}